// Round 1
// 564.149 us; speedup vs baseline: 1.0645x; 1.0645x over previous
//
#include <hip/hip_runtime.h>
#include <stdint.h>

// Sizes (fixed by the problem)
#define BATCH   65536
#define D_IN    784
#define KP      832      // D_IN padded to a multiple of BK=64
#define HDIM    512
#define D_OUT   10
#define NCODE   512
#define HT_LD   136      // epilogue LDS tile leading dim (128 + 8 f16 pad)

typedef _Float16 f16;
typedef _Float16 f16x8 __attribute__((ext_vector_type(8)));
typedef float    f32x4 __attribute__((ext_vector_type(4)));

__device__ __forceinline__ void gld_lds16(const void* g, void* l) {
  __builtin_amdgcn_global_load_lds((const __attribute__((address_space(1))) void*)g,
                                   (__attribute__((address_space(3))) void*)l, 16, 0, 0);
}

// ---------------- VQ W1: blocks (og<128, ig<112), dim 28 ----------------
// Replicates numpy-fp32 semantics (verified R3: absmax 454 -> 0.0156):
//   dist = fl(fl(s - 2*dot) + t); s = numpy pairwise scalar 8-acc; dot =
//   ascending-k fp32 FMA chain; t = sequential axis-0 sum; first-min argmin.
__global__ void k_vq1(const float* __restrict__ W1, const float* __restrict__ E1,
                      f16* __restrict__ qW1, float* __restrict__ diffacc) {
  #pragma clang fp contract(off)
  __shared__ float E1s[28 * NCODE];
  __shared__ float Ts[NCODE];
  for (int i = threadIdx.x; i < 28 * NCODE; i += 256) E1s[i] = E1[i];
  __syncthreads();
  for (int k = threadIdx.x; k < NCODE; k += 256) {
    float e0 = E1s[k];
    float t = e0 * e0;
    for (int j = 1; j < 28; ++j) {
      float e = E1s[j * NCODE + k];
      float ee = e * e;
      t = t + ee;
    }
    Ts[k] = t;
  }
  __syncthreads();
  const int wid = threadIdx.x >> 6, lane = threadIdx.x & 63;
  const int bid = blockIdx.x * 4 + wid;          // < 14336
  const int og = bid / 112, ig = bid % 112;
  float v[28], vv[28];
  #pragma unroll
  for (int j = 0; j < 28; ++j) {
    int om = j & 3, im = j >> 2;
    v[j] = W1[(og * 4 + om) * D_IN + ig * 7 + im];
    vv[j] = v[j] * v[j];
  }
  float r[8];
  #pragma unroll
  for (int j = 0; j < 8; ++j) r[j] = vv[j];
  #pragma unroll
  for (int j = 0; j < 8; ++j) r[j] = r[j] + vv[8 + j];
  #pragma unroll
  for (int j = 0; j < 8; ++j) r[j] = r[j] + vv[16 + j];
  float s = ((r[0] + r[1]) + (r[2] + r[3])) + ((r[4] + r[5]) + (r[6] + r[7]));
  s = s + vv[24]; s = s + vv[25]; s = s + vv[26]; s = s + vv[27];

  float bestd = 1e30f; int bestk = 0x7fffffff;
  for (int t = 0; t < 8; ++t) {
    int k = t * 64 + lane;
    float dot = 0.f;
    #pragma unroll
    for (int j = 0; j < 28; ++j) dot = __builtin_fmaf(v[j], E1s[j * NCODE + k], dot);
    float d = (s - 2.0f * dot) + Ts[k];
    if (d < bestd || (d == bestd && k < bestk)) { bestd = d; bestk = k; }
  }
  for (int off = 32; off; off >>= 1) {
    float d2 = __shfl_down(bestd, off, 64);
    int   k2 = __shfl_down(bestk, off, 64);
    if (d2 < bestd || (d2 == bestd && k2 < bestk)) { bestd = d2; bestk = k2; }
  }
  int kstar = __shfl(bestk, 0, 64);
  float sq = 0.f;
  if (lane < 28) {
    int om = lane & 3, im = lane >> 2;
    float q = E1s[lane * NCODE + kstar];
    qW1[(size_t)(og * 4 + om) * KP + ig * 7 + im] = (f16)q;
    float dd = q - v[lane]; sq = dd * dd;
  }
  for (int off = 32; off; off >>= 1) sq += __shfl_down(sq, off, 64);
  if (lane == 0) atomicAdd(&diffacc[bid & 127], sq);
}

// ---------------- VQ W2: blocks (og<512, ig<32), dim 16 contiguous ----------------
__global__ void k_vq2(const float* __restrict__ W2, const float* __restrict__ E2,
                      f16* __restrict__ qW2, float* __restrict__ diffacc) {
  #pragma clang fp contract(off)
  __shared__ float E2s[16 * NCODE];
  __shared__ float Ts[NCODE];
  for (int i = threadIdx.x; i < 16 * NCODE; i += 256) E2s[i] = E2[i];
  __syncthreads();
  for (int k = threadIdx.x; k < NCODE; k += 256) {
    float e0 = E2s[k];
    float t = e0 * e0;
    for (int j = 1; j < 16; ++j) {
      float e = E2s[j * NCODE + k];
      float ee = e * e;
      t = t + ee;
    }
    Ts[k] = t;
  }
  __syncthreads();
  const int wid = threadIdx.x >> 6, lane = threadIdx.x & 63;
  const int bid = blockIdx.x * 4 + wid;          // < 16384
  const int og = bid >> 5, ig = bid & 31;
  float v[16], vv[16];
  #pragma unroll
  for (int j = 0; j < 16; ++j) {
    v[j] = W2[og * HDIM + ig * 16 + j];
    vv[j] = v[j] * v[j];
  }
  float r[8];
  #pragma unroll
  for (int j = 0; j < 8; ++j) r[j] = vv[j];
  #pragma unroll
  for (int j = 0; j < 8; ++j) r[j] = r[j] + vv[8 + j];
  float s = ((r[0] + r[1]) + (r[2] + r[3])) + ((r[4] + r[5]) + (r[6] + r[7]));

  float bestd = 1e30f; int bestk = 0x7fffffff;
  for (int t = 0; t < 8; ++t) {
    int k = t * 64 + lane;
    float dot = 0.f;
    #pragma unroll
    for (int j = 0; j < 16; ++j) dot = __builtin_fmaf(v[j], E2s[j * NCODE + k], dot);
    float d = (s - 2.0f * dot) + Ts[k];
    if (d < bestd || (d == bestd && k < bestk)) { bestd = d; bestk = k; }
  }
  for (int off = 32; off; off >>= 1) {
    float d2 = __shfl_down(bestd, off, 64);
    int   k2 = __shfl_down(bestk, off, 64);
    if (d2 < bestd || (d2 == bestd && k2 < bestk)) { bestd = d2; bestk = k2; }
  }
  int kstar = __shfl(bestk, 0, 64);
  float sq = 0.f;
  if (lane < 16) {
    float q = E2s[lane * NCODE + kstar];
    qW2[(size_t)og * HDIM + ig * 16 + lane] = (f16)q;
    float dd = q - v[lane]; sq = dd * dd;
  }
  for (int off = 32; off; off >>= 1) sq += __shfl_down(sq, off, 64);
  if (lane == 0) atomicAdd(&diffacc[bid & 127], sq);
}

// ---------------- GEMM1: h = relu(x @ qW1^T + b1), fused fp32->f16 convert + column stats ----
// A staged from fp32 x via regs (cvt RTN, identical to old k_convert_x path);
// B via global_load_lds. BK=64 as two [128][32] sub-tiles. XCD-swizzled blockIdx.
__global__ void __launch_bounds__(256, 4)
k_gemm1(const float* __restrict__ X, const f16* __restrict__ Bw,
        const float* __restrict__ bias, f16* __restrict__ C,
        float* __restrict__ statacc) {
  __shared__ __align__(16) char lds_all[HT_LD * 128 * 2];   // 34816 B union (>= 32 KB staging)
  __shared__ float cls[128], cls2[128];
  f16* As = (f16*)lds_all;                 // [2][128][32] f16 = 16 KB
  f16* Bs = (f16*)(lds_all + 16384);       // [2][128][32] f16 = 16 KB
  f16* ht = (f16*)lds_all;
  const int tid = threadIdx.x;
  // XCD swizzle: consecutive logical ids (4 bn-siblings of one bm) -> same XCD
  const int logical = ((blockIdx.x & 7) << 8) + (blockIdx.x >> 3);  // 2048 blocks, bijective
  const int bn = logical & 3;
  const int bm = logical >> 2;
  const int lane = tid & 63, wid = tid >> 6;
  const int waveM = wid & 1, waveN = wid >> 1;
  const int l15 = lane & 15, quad = lane >> 4;

  if (tid < 128) cls[tid] = 0.f; else cls2[tid - 128] = 0.f;

  // B staging: 4 slots/thread, dest linear (global_load_lds), src [2][128][32] decode
  const f16* gB[4]; f16* lB[4];
  #pragma unroll
  for (int s = 0; s < 4; ++s) {
    int slot = tid + s * 256;
    int ks = slot >> 9, r2 = (slot >> 2) & 127, c = slot & 3;
    gB[s] = Bw + (size_t)(bn * 128 + r2) * KP + ks * 32 + c * 8;
    lB[s] = Bs + slot * 8;
  }
  // A staging: 4 slots/thread from fp32 x; slot decode matches B dest layout
  const int cA = tid & 3;
  const float* gA[4]; f16* lA[4];
  #pragma unroll
  for (int s = 0; s < 4; ++s) {
    int r2 = (tid >> 2) + (s & 1) * 64;
    gA[s] = X + (size_t)(bm * 128 + r2) * D_IN + (s >> 1) * 32 + cA * 8;
    lA[s] = As + (tid + s * 256) * 8;
  }

  f32x4 acc[4][4];
  #pragma unroll
  for (int i = 0; i < 4; ++i)
    #pragma unroll
    for (int j = 0; j < 4; ++j) acc[i][j] = (f32x4){0.f, 0.f, 0.f, 0.f};

  const int aoff = (waveM * 64 + l15) * 32 + quad * 8;
  const int boff = (waveN * 64 + l15) * 32 + quad * 8;

  for (int k0 = 0; k0 < KP; k0 += 64) {
    #pragma unroll
    for (int s = 0; s < 4; ++s) gld_lds16(gB[s] + k0, lB[s]);
    float4 ra[8];
    #pragma unroll
    for (int s = 0; s < 4; ++s) {
      int gcol = k0 + (s >> 1) * 32 + cA * 8;
      ra[2 * s]     = (float4){0.f, 0.f, 0.f, 0.f};
      ra[2 * s + 1] = (float4){0.f, 0.f, 0.f, 0.f};
      if (gcol < D_IN) {            // D_IN % 8 == 0: chunks fully valid or fully pad
        ra[2 * s]     = *(const float4*)(gA[s] + k0);
        ra[2 * s + 1] = *(const float4*)(gA[s] + k0 + 4);
      }
    }
    #pragma unroll
    for (int s = 0; s < 4; ++s) {
      f16x8 o;
      o[0] = (f16)ra[2 * s].x;     o[1] = (f16)ra[2 * s].y;
      o[2] = (f16)ra[2 * s].z;     o[3] = (f16)ra[2 * s].w;
      o[4] = (f16)ra[2 * s + 1].x; o[5] = (f16)ra[2 * s + 1].y;
      o[6] = (f16)ra[2 * s + 1].z; o[7] = (f16)ra[2 * s + 1].w;
      *(f16x8*)lA[s] = o;
    }
    __syncthreads();
    #pragma unroll
    for (int ks = 0; ks < 2; ++ks) {       // ascending k: same accumulation order as BK=32
      f16x8 af[4], bf[4];
      #pragma unroll
      for (int i = 0; i < 4; ++i) af[i] = *(const f16x8*)(As + ks * 4096 + aoff + i * 512);
      #pragma unroll
      for (int j = 0; j < 4; ++j) bf[j] = *(const f16x8*)(Bs + ks * 4096 + boff + j * 512);
      #pragma unroll
      for (int i = 0; i < 4; ++i)
        #pragma unroll
        for (int j = 0; j < 4; ++j)
          acc[i][j] = __builtin_amdgcn_mfma_f32_16x16x32_f16(af[i], bf[j], acc[i][j], 0, 0, 0);
    }
    __syncthreads();
  }
  // epilogue: relu+bias -> LDS tile (f16) + per-column stats on fp32 values
  const int colbase = bn * 128 + waveN * 64 + l15;
  float bcol[4];
  #pragma unroll
  for (int j = 0; j < 4; ++j) bcol[j] = bias[colbase + j * 16];
  float cs[4] = {0.f,0.f,0.f,0.f}, cs2[4] = {0.f,0.f,0.f,0.f};
  #pragma unroll
  for (int i = 0; i < 4; ++i)
    #pragma unroll
    for (int r2 = 0; r2 < 4; ++r2) {
      int rloc = waveM * 64 + quad * 4 + i * 16 + r2;
      #pragma unroll
      for (int j = 0; j < 4; ++j) {
        float v = acc[i][j][r2] + bcol[j];
        v = v > 0.f ? v : 0.f;
        ht[rloc * HT_LD + waveN * 64 + j * 16 + l15] = (f16)v;
        cs[j] += v; cs2[j] += v * v;
      }
    }
  // reduce over quads (same column), then LDS atomics by quad==0 lanes
  #pragma unroll
  for (int j = 0; j < 4; ++j) {
    cs[j]  += __shfl_xor(cs[j], 16, 64);  cs[j]  += __shfl_xor(cs[j], 32, 64);
    cs2[j] += __shfl_xor(cs2[j], 16, 64); cs2[j] += __shfl_xor(cs2[j], 32, 64);
  }
  if (quad == 0) {
    #pragma unroll
    for (int j = 0; j < 4; ++j) {
      atomicAdd(&cls[waveN * 64 + j * 16 + l15], cs[j]);
      atomicAdd(&cls2[waveN * 64 + j * 16 + l15], cs2[j]);
    }
  }
  __syncthreads();
  if (tid < 128) atomicAdd(&statacc[256 + bn * 128 + tid], cls[tid]);
  else           atomicAdd(&statacc[768 + bn * 128 + (tid - 128)], cls2[tid - 128]);
  // coalesced h write-back: thread t -> row t>>1, 64-col half t&1
  {
    const int rloc = tid >> 1, half = tid & 1;
    f16* crow = C + (size_t)(bm * 128 + rloc) * HDIM + bn * 128 + half * 64;
    const f16* srow = ht + rloc * HT_LD + half * 64;
    #pragma unroll
    for (int j = 0; j < 8; ++j)
      *(f16x8*)(crow + j * 8) = *(const f16x8*)(srow + j * 8);
  }
}

// ---------------- BN coefficients + diff output + W3 f16 (padded 10->16 rows) ----------------
__global__ void k_bnprep(const float* __restrict__ acc, const float* __restrict__ gamma,
                         const float* __restrict__ beta, float* __restrict__ ab,
                         const float* __restrict__ W3, f16* __restrict__ W3h,
                         float* __restrict__ diff_out) {
  const int c = threadIdx.x;                        // 512 threads
  const float inv = 1.f / 65536.f;
  float mu = acc[256 + c] * inv;
  float msq = acc[768 + c] * inv;
  float var = msq - mu * mu;
  float a = gamma[c] / sqrtf(var + 1e-5f);
  ab[c] = a;
  ab[512 + c] = beta[c] - mu * a;
  #pragma unroll
  for (int o = 0; o < 16; ++o)
    W3h[o * HDIM + c] = (o < D_OUT) ? (f16)W3[o * HDIM + c] : (f16)0.f;
  if (c == 0) {
    float s1 = 0.f, s2 = 0.f;
    for (int i = 0; i < 128; ++i) { s1 += acc[i]; s2 += acc[128 + i]; }
    diff_out[0] = s1 * (1.f / 401408.f) + s2 * (1.f / 262144.f);
  }
}

// ---------------- fold BN into qW2 (in place) + bias2 ----------------
// bn(h)@qW2^T = h@(a.*qW2)^T + [b2 + sum_k b[k]*qW2[:,k]]
__global__ void k_bnfold(f16* __restrict__ qW2, const float* __restrict__ ab,
                         const float* __restrict__ b2, float* __restrict__ bias2) {
  __shared__ float red[256];
  const int n = blockIdx.x, t = threadIdx.x;        // 512 blocks x 256 threads
  float partial = 0.f;
  #pragma unroll
  for (int kk = 0; kk < 2; ++kk) {
    int k = t + kk * 256;
    float w = (float)qW2[n * HDIM + k];
    partial += ab[512 + k] * w;
    qW2[n * HDIM + k] = (f16)(ab[k] * w);
  }
  red[t] = partial; __syncthreads();
  for (int s = 128; s > 0; s >>= 1) { if (t < s) red[t] += red[t + s]; __syncthreads(); }
  if (t == 0) bias2[n] = b2[n] + red[0];
}

// ---------------- GEMM2 + fused final layer ----------------
// h2tile = relu(h @ qW2s^T + bias2) -> LDS; out += h2tile @ W3h[:, bn*128..]^T (+b3 once, bn==0)
// BK=64 as two [128][32] sub-tiles; XCD-swizzled blockIdx.
__global__ void __launch_bounds__(256, 4)
k_gemm2f(const f16* __restrict__ A, const f16* __restrict__ Bw,
         const float* __restrict__ bias2, const f16* __restrict__ W3h,
         const float* __restrict__ b3, float* __restrict__ out) {
  __shared__ __align__(16) char lds_all[HT_LD * 128 * 2];   // 34816 B union
  f16* As = (f16*)lds_all;                 // [2][128][32]
  f16* Bs = (f16*)(lds_all + 16384);       // [2][128][32]
  f16* ht = (f16*)lds_all;
  const int tid = threadIdx.x;
  const int logical = ((blockIdx.x & 7) << 8) + (blockIdx.x >> 3);  // XCD swizzle
  const int bn = logical & 3;
  const int bm = logical >> 2;
  const int lane = tid & 63, wid = tid >> 6;
  const int waveM = wid & 1, waveN = wid >> 1;
  const int l15 = lane & 15, quad = lane >> 4;

  const f16* gA[4]; const f16* gB[4]; f16* lA[4]; f16* lB[4];
  #pragma unroll
  for (int s = 0; s < 4; ++s) {
    int slot = tid + s * 256;
    int ks = slot >> 9, r2 = (slot >> 2) & 127, c = slot & 3;
    gA[s] = A  + (size_t)(bm * 128 + r2) * HDIM + ks * 32 + c * 8;
    gB[s] = Bw + (size_t)(bn * 128 + r2) * HDIM + ks * 32 + c * 8;
    lA[s] = As + slot * 8;
    lB[s] = Bs + slot * 8;
  }

  f32x4 acc[4][4];
  #pragma unroll
  for (int i = 0; i < 4; ++i)
    #pragma unroll
    for (int j = 0; j < 4; ++j) acc[i][j] = (f32x4){0.f, 0.f, 0.f, 0.f};

  const int aoff = (waveM * 64 + l15) * 32 + quad * 8;
  const int boff = (waveN * 64 + l15) * 32 + quad * 8;

  for (int k0 = 0; k0 < HDIM; k0 += 64) {
    #pragma unroll
    for (int s = 0; s < 4; ++s) {
      gld_lds16(gA[s] + k0, lA[s]);
      gld_lds16(gB[s] + k0, lB[s]);
    }
    __syncthreads();
    #pragma unroll
    for (int ks = 0; ks < 2; ++ks) {
      f16x8 af[4], bf[4];
      #pragma unroll
      for (int i = 0; i < 4; ++i) af[i] = *(const f16x8*)(As + ks * 4096 + aoff + i * 512);
      #pragma unroll
      for (int j = 0; j < 4; ++j) bf[j] = *(const f16x8*)(Bs + ks * 4096 + boff + j * 512);
      #pragma unroll
      for (int i = 0; i < 4; ++i)
        #pragma unroll
        for (int j = 0; j < 4; ++j)
          acc[i][j] = __builtin_amdgcn_mfma_f32_16x16x32_f16(af[i], bf[j], acc[i][j], 0, 0, 0);
    }
    __syncthreads();
  }
  // epilogue: relu+bias2 -> LDS f16 tile (no global h2)
  const int colbase = bn * 128 + waveN * 64 + l15;
  float bcol[4];
  #pragma unroll
  for (int j = 0; j < 4; ++j) bcol[j] = bias2[colbase + j * 16];
  #pragma unroll
  for (int i = 0; i < 4; ++i)
    #pragma unroll
    for (int r2 = 0; r2 < 4; ++r2) {
      int rloc = waveM * 64 + quad * 4 + i * 16 + r2;
      #pragma unroll
      for (int j = 0; j < 4; ++j) {
        float v = acc[i][j][r2] + bcol[j];
        v = v > 0.f ? v : 0.f;
        ht[rloc * HT_LD + waveN * 64 + j * 16 + l15] = (f16)v;
      }
    }
  __syncthreads();
  // final layer: rows [wid*32, wid*32+32), N=16 (W3h padded), K=128 = this tile's
  // columns bn*128..bn*128+127 -> W3h columns MUST be offset by bn*128 (R4 bug).
  f32x4 oacc[2];
  oacc[0] = (f32x4){0.f,0.f,0.f,0.f}; oacc[1] = (f32x4){0.f,0.f,0.f,0.f};
  #pragma unroll
  for (int ks = 0; ks < 4; ++ks) {
    f16x8 bfr = *(const f16x8*)(W3h + l15 * HDIM + bn * 128 + ks * 32 + quad * 8);
    #pragma unroll
    for (int i2 = 0; i2 < 2; ++i2) {
      f16x8 afr = *(const f16x8*)(ht + (wid * 32 + i2 * 16 + l15) * HT_LD + ks * 32 + quad * 8);
      oacc[i2] = __builtin_amdgcn_mfma_f32_16x16x32_f16(afr, bfr, oacc[i2], 0, 0, 0);
    }
  }
  if (l15 < D_OUT) {
    float badd = (bn == 0) ? b3[l15] : 0.f;
    #pragma unroll
    for (int i2 = 0; i2 < 2; ++i2)
      #pragma unroll
      for (int r2 = 0; r2 < 4; ++r2) {
        int row = bm * 128 + wid * 32 + i2 * 16 + quad * 4 + r2;
        atomicAdd(&out[(size_t)row * D_OUT + l15], oacc[i2][r2] + badd);
      }
  }
}

extern "C" void kernel_launch(void* const* d_in, const int* in_sizes, int n_in,
                              void* d_out, int out_size, void* d_ws, size_t ws_size,
                              hipStream_t stream) {
  const float* x     = (const float*)d_in[0];
  const float* W1    = (const float*)d_in[1];
  const float* b1    = (const float*)d_in[2];
  const float* gamma = (const float*)d_in[3];
  const float* beta  = (const float*)d_in[4];
  const float* E1    = (const float*)d_in[5];
  const float* W2    = (const float*)d_in[6];
  const float* b2    = (const float*)d_in[7];
  const float* E2    = (const float*)d_in[8];
  const float* W3    = (const float*)d_in[9];
  const float* b3    = (const float*)d_in[10];
  float* out = (float*)d_out;

  char* ws = (char*)d_ws;
  float* accum = (float*)ws;                       // [0,128) diff1, [128,256) diff2, [256,768) colsum, [768,1280) colsumsq
  f16* qW1h = (f16*)(ws + 8192);                   // 512*832*2 = 851968
  f16* qW2h = (f16*)(ws + 860160);                 // 512*512*2 = 524288
  f16* W3h  = (f16*)(ws + 1384448);                // 16*512*2  = 16384
  float* ab = (float*)(ws + 1400832);              // 1024*4
  float* bias2 = (float*)(ws + 1404928);           // 512*4
  f16* h    = (f16*)(ws + 1409024);                // 65536*512*2 = 67108864

  hipMemsetAsync(ws, 0, 860160, stream);           // accum + qW1h (zero K-padding)
  hipMemsetAsync(d_out, 0, (size_t)out_size * 4, stream);  // out accumulated via atomics
  k_vq1<<<3584, 256, 0, stream>>>(W1, E1, qW1h, accum);
  k_vq2<<<4096, 256, 0, stream>>>(W2, E2, qW2h, accum + 128);
  k_gemm1<<<2048, 256, 0, stream>>>(x, qW1h, b1, h, accum);
  k_bnprep<<<1, 512, 0, stream>>>(accum, gamma, beta, ab, W3, W3h, out + (size_t)BATCH * D_OUT);
  k_bnfold<<<512, 256, 0, stream>>>(qW2h, ab, b2, bias2);
  k_gemm2f<<<2048, 256, 0, stream>>>(h, qW2h, bias2, W3h, b3, out);
}

// Round 2
// 545.923 us; speedup vs baseline: 1.1000x; 1.0334x over previous
//
#include <hip/hip_runtime.h>
#include <stdint.h>

// Sizes (fixed by the problem)
#define BATCH   65536
#define D_IN    784
#define KP      800      // D_IN padded to a multiple of BK=32
#define HDIM    512
#define D_OUT   10
#define NCODE   512
#define HT_LD   136      // epilogue LDS tile leading dim (128 + 8 f16 pad)

typedef _Float16 f16;
typedef _Float16 f16x8 __attribute__((ext_vector_type(8)));
typedef float    f32x4 __attribute__((ext_vector_type(4)));

__device__ __forceinline__ void gld_lds16(const void* g, void* l) {
  __builtin_amdgcn_global_load_lds((const __attribute__((address_space(1))) void*)g,
                                   (__attribute__((address_space(3))) void*)l, 16, 0, 0);
}

#define MEMFENCE asm volatile("" ::: "memory")
#define BARRIER() do { MEMFENCE; __builtin_amdgcn_s_barrier(); MEMFENCE; } while (0)

// ---------------- VQ W1: blocks (og<128, ig<112), dim 28 ----------------
// Replicates numpy-fp32 semantics (verified: absmax 0.0156):
//   dist = fl(fl(s - 2*dot) + t); s = numpy pairwise scalar 8-acc; dot =
//   ascending-k fp32 FMA chain; t = sequential axis-0 sum; first-min argmin.
__global__ void k_vq1(const float* __restrict__ W1, const float* __restrict__ E1,
                      f16* __restrict__ qW1, float* __restrict__ diffacc) {
  #pragma clang fp contract(off)
  __shared__ float E1s[28 * NCODE];
  __shared__ float Ts[NCODE];
  for (int i = threadIdx.x; i < 28 * NCODE; i += 256) E1s[i] = E1[i];
  __syncthreads();
  for (int k = threadIdx.x; k < NCODE; k += 256) {
    float e0 = E1s[k];
    float t = e0 * e0;
    for (int j = 1; j < 28; ++j) {
      float e = E1s[j * NCODE + k];
      float ee = e * e;
      t = t + ee;
    }
    Ts[k] = t;
  }
  __syncthreads();
  const int wid = threadIdx.x >> 6, lane = threadIdx.x & 63;
  const int bid = blockIdx.x * 4 + wid;          // < 14336
  const int og = bid / 112, ig = bid % 112;
  float v[28], vv[28];
  #pragma unroll
  for (int j = 0; j < 28; ++j) {
    int om = j & 3, im = j >> 2;
    v[j] = W1[(og * 4 + om) * D_IN + ig * 7 + im];
    vv[j] = v[j] * v[j];
  }
  float r[8];
  #pragma unroll
  for (int j = 0; j < 8; ++j) r[j] = vv[j];
  #pragma unroll
  for (int j = 0; j < 8; ++j) r[j] = r[j] + vv[8 + j];
  #pragma unroll
  for (int j = 0; j < 8; ++j) r[j] = r[j] + vv[16 + j];
  float s = ((r[0] + r[1]) + (r[2] + r[3])) + ((r[4] + r[5]) + (r[6] + r[7]));
  s = s + vv[24]; s = s + vv[25]; s = s + vv[26]; s = s + vv[27];

  float bestd = 1e30f; int bestk = 0x7fffffff;
  for (int t = 0; t < 8; ++t) {
    int k = t * 64 + lane;
    float dot = 0.f;
    #pragma unroll
    for (int j = 0; j < 28; ++j) dot = __builtin_fmaf(v[j], E1s[j * NCODE + k], dot);
    float d = (s - 2.0f * dot) + Ts[k];
    if (d < bestd || (d == bestd && k < bestk)) { bestd = d; bestk = k; }
  }
  for (int off = 32; off; off >>= 1) {
    float d2 = __shfl_down(bestd, off, 64);
    int   k2 = __shfl_down(bestk, off, 64);
    if (d2 < bestd || (d2 == bestd && k2 < bestk)) { bestd = d2; bestk = k2; }
  }
  int kstar = __shfl(bestk, 0, 64);
  float sq = 0.f;
  if (lane < 28) {
    int om = lane & 3, im = lane >> 2;
    float q = E1s[lane * NCODE + kstar];
    qW1[(size_t)(og * 4 + om) * KP + ig * 7 + im] = (f16)q;
    float dd = q - v[lane]; sq = dd * dd;
  }
  for (int off = 32; off; off >>= 1) sq += __shfl_down(sq, off, 64);
  if (lane == 0) atomicAdd(&diffacc[bid & 127], sq);
}

// ---------------- VQ W2: blocks (og<512, ig<32), dim 16 contiguous ----------------
__global__ void k_vq2(const float* __restrict__ W2, const float* __restrict__ E2,
                      f16* __restrict__ qW2, float* __restrict__ diffacc) {
  #pragma clang fp contract(off)
  __shared__ float E2s[16 * NCODE];
  __shared__ float Ts[NCODE];
  for (int i = threadIdx.x; i < 16 * NCODE; i += 256) E2s[i] = E2[i];
  __syncthreads();
  for (int k = threadIdx.x; k < NCODE; k += 256) {
    float e0 = E2s[k];
    float t = e0 * e0;
    for (int j = 1; j < 16; ++j) {
      float e = E2s[j * NCODE + k];
      float ee = e * e;
      t = t + ee;
    }
    Ts[k] = t;
  }
  __syncthreads();
  const int wid = threadIdx.x >> 6, lane = threadIdx.x & 63;
  const int bid = blockIdx.x * 4 + wid;          // < 16384
  const int og = bid >> 5, ig = bid & 31;
  float v[16], vv[16];
  #pragma unroll
  for (int j = 0; j < 16; ++j) {
    v[j] = W2[og * HDIM + ig * 16 + j];
    vv[j] = v[j] * v[j];
  }
  float r[8];
  #pragma unroll
  for (int j = 0; j < 8; ++j) r[j] = vv[j];
  #pragma unroll
  for (int j = 0; j < 8; ++j) r[j] = r[j] + vv[8 + j];
  float s = ((r[0] + r[1]) + (r[2] + r[3])) + ((r[4] + r[5]) + (r[6] + r[7]));

  float bestd = 1e30f; int bestk = 0x7fffffff;
  for (int t = 0; t < 8; ++t) {
    int k = t * 64 + lane;
    float dot = 0.f;
    #pragma unroll
    for (int j = 0; j < 16; ++j) dot = __builtin_fmaf(v[j], E2s[j * NCODE + k], dot);
    float d = (s - 2.0f * dot) + Ts[k];
    if (d < bestd || (d == bestd && k < bestk)) { bestd = d; bestk = k; }
  }
  for (int off = 32; off; off >>= 1) {
    float d2 = __shfl_down(bestd, off, 64);
    int   k2 = __shfl_down(bestk, off, 64);
    if (d2 < bestd || (d2 == bestd && k2 < bestk)) { bestd = d2; bestk = k2; }
  }
  int kstar = __shfl(bestk, 0, 64);
  float sq = 0.f;
  if (lane < 16) {
    float q = E2s[lane * NCODE + kstar];
    qW2[(size_t)og * HDIM + ig * 16 + lane] = (f16)q;
    float dd = q - v[lane]; sq = dd * dd;
  }
  for (int off = 32; off; off >>= 1) sq += __shfl_down(sq, off, 64);
  if (lane == 0) atomicAdd(&diffacc[bid & 127], sq);
}

// ---------------- GEMM1: h = relu(x @ qW1^T + b1), fused cvt + column stats ----------
// Double-buffered LDS, single raw barrier per K-step, counted vmcnt so the
// A-register prefetch (issued one iteration ahead) and B global_load_lds stay
// in flight across the barrier (T3/T4/T14). XCD-swizzled blockIdx.
// vmcnt ledger per steady-state iter k (issue order is pinned by MEMFENCEs):
//   outstanding at writeA: A(k+1)[4 oldest] + B(k+1)[2]  -> wait vmcnt(2)
//   after issueA(k+2):     B(k+1)[2 oldest] + A(k+2)[4]  -> wait vmcnt(4)
// A loads are UNCONDITIONAL (clamped col + zero at consume) so counts are exact.
__global__ void __launch_bounds__(256, 4)
k_gemm1(const float* __restrict__ X, const f16* __restrict__ Bw,
        const float* __restrict__ bias, f16* __restrict__ C,
        float* __restrict__ statacc) {
  __shared__ __align__(16) char lds_all[HT_LD * 128 * 2];   // 34816 B union
  __shared__ float cls[128], cls2[128];
  f16* ht = (f16*)lds_all;
  const int tid = threadIdx.x;
  const int logical = ((blockIdx.x & 7) << 8) + (blockIdx.x >> 3);  // XCD swizzle, bijective
  const int bn = logical & 3;
  const int bm = logical >> 2;
  const int lane = tid & 63, wid = tid >> 6;
  const int waveM = wid & 1, waveN = wid >> 1;
  const int l15 = lane & 15, quad = lane >> 4;

  if (tid < 128) cls[tid] = 0.f; else cls2[tid - 128] = 0.f;

  // slot decode (slot = tid, tid+256): row = slot>>2, col8 = slot&3; LDS elem = slot*8
  const int cA = tid & 3;
  const int r0 = tid >> 2;
  const float* gX0 = X + (size_t)(bm * 128 + r0) * D_IN;
  const float* gX1 = gX0 + (size_t)64 * D_IN;
  const f16*  gB0 = Bw + (size_t)(bn * 128 + r0) * KP + cA * 8;
  const f16*  gB1 = gB0 + (size_t)64 * KP;

  f32x4 acc[4][4];
  #pragma unroll
  for (int i = 0; i < 4; ++i)
    #pragma unroll
    for (int j = 0; j < 4; ++j) acc[i][j] = (f32x4){0.f, 0.f, 0.f, 0.f};

  const int aoff = (waveM * 64 + l15) * 32 + quad * 8;
  const int boff = (waveN * 64 + l15) * 32 + quad * 8;

  float4 ra0, ra1, ra2, ra3;
  auto issueA = [&](int k0) {
    int gc = k0 + cA * 8;
    int gco = gc < D_IN ? gc : 0;          // clamp: always issue 4 loads (vmcnt determinism)
    ra0 = *(const float4*)(gX0 + gco);
    ra1 = *(const float4*)(gX0 + gco + 4);
    ra2 = *(const float4*)(gX1 + gco);
    ra3 = *(const float4*)(gX1 + gco + 4);
  };
  auto writeA = [&](int k0, f16* dstA) {
    bool valid = (k0 + cA * 8) < D_IN;
    float4 a0 = ra0, a1 = ra1, b0 = ra2, b1 = ra3;
    if (!valid) {
      a0 = (float4){0.f,0.f,0.f,0.f}; a1 = a0; b0 = a0; b1 = a0;
    }
    f16x8 o0, o1;
    o0[0]=(f16)a0.x; o0[1]=(f16)a0.y; o0[2]=(f16)a0.z; o0[3]=(f16)a0.w;
    o0[4]=(f16)a1.x; o0[5]=(f16)a1.y; o0[6]=(f16)a1.z; o0[7]=(f16)a1.w;
    o1[0]=(f16)b0.x; o1[1]=(f16)b0.y; o1[2]=(f16)b0.z; o1[3]=(f16)b0.w;
    o1[4]=(f16)b1.x; o1[5]=(f16)b1.y; o1[6]=(f16)b1.z; o1[7]=(f16)b1.w;
    *(f16x8*)(dstA + tid * 8) = o0;
    *(f16x8*)(dstA + tid * 8 + 2048) = o1;
  };
  auto issueB = [&](int k0, f16* dstB) {
    gld_lds16(gB0 + k0, dstB + tid * 8);
    gld_lds16(gB1 + k0, dstB + tid * 8 + 2048);
  };
  auto mma = [&](const f16* A_, const f16* B_) {
    f16x8 af[4], bf[4];
    #pragma unroll
    for (int i = 0; i < 4; ++i) af[i] = *(const f16x8*)(A_ + aoff + i * 512);
    #pragma unroll
    for (int j = 0; j < 4; ++j) bf[j] = *(const f16x8*)(B_ + boff + j * 512);
    #pragma unroll
    for (int i = 0; i < 4; ++i)
      #pragma unroll
      for (int j = 0; j < 4; ++j)
        acc[i][j] = __builtin_amdgcn_mfma_f32_16x16x32_f16(af[i], bf[j], acc[i][j], 0, 0, 0);
  };

  const int NT = KP / 32;                  // 25
  // LDS tiles: As0 @0, As1 @8192, Bs0 @16384, Bs1 @24576 (bytes)
  // prologue
  issueA(0);
  MEMFENCE;
  issueB(0, (f16*)(lds_all + 16384));
  MEMFENCE;
  writeA(0, (f16*)lds_all);
  issueA(32);
  asm volatile("s_waitcnt vmcnt(4) lgkmcnt(0)" ::: "memory");   // B(0) landed, ds_writes done
  BARRIER();

  for (int k = 0; k < NT; ++k) {
    const int cur = k & 1;
    f16* Asc = (f16*)(lds_all + cur * 8192);
    f16* Bsc = (f16*)(lds_all + 16384 + cur * 8192);
    f16* Asn = (f16*)(lds_all + (cur ^ 1) * 8192);
    f16* Bsn = (f16*)(lds_all + 16384 + (cur ^ 1) * 8192);
    if (k + 1 < NT) issueB((k + 1) * 32, Bsn);
    MEMFENCE;
    __builtin_amdgcn_s_setprio(1);
    mma(Asc, Bsc);
    __builtin_amdgcn_s_setprio(0);
    if (k + 1 < NT) {
      writeA((k + 1) * 32, Asn);           // compiler waits A(k+1) regs (in flight 1 iter)
      if (k + 2 < NT) {
        issueA((k + 2) * 32);
        asm volatile("s_waitcnt vmcnt(4) lgkmcnt(0)" ::: "memory");  // B(k+1) landed
      } else {
        asm volatile("s_waitcnt vmcnt(0) lgkmcnt(0)" ::: "memory");
      }
    }
    BARRIER();
  }
  // epilogue: relu+bias -> LDS tile (f16) + per-column stats on fp32 values
  const int colbase = bn * 128 + waveN * 64 + l15;
  float bcol[4];
  #pragma unroll
  for (int j = 0; j < 4; ++j) bcol[j] = bias[colbase + j * 16];
  float cs[4] = {0.f,0.f,0.f,0.f}, cs2[4] = {0.f,0.f,0.f,0.f};
  #pragma unroll
  for (int i = 0; i < 4; ++i)
    #pragma unroll
    for (int r2 = 0; r2 < 4; ++r2) {
      int rloc = waveM * 64 + quad * 4 + i * 16 + r2;
      #pragma unroll
      for (int j = 0; j < 4; ++j) {
        float v = acc[i][j][r2] + bcol[j];
        v = v > 0.f ? v : 0.f;
        ht[rloc * HT_LD + waveN * 64 + j * 16 + l15] = (f16)v;
        cs[j] += v; cs2[j] += v * v;
      }
    }
  #pragma unroll
  for (int j = 0; j < 4; ++j) {
    cs[j]  += __shfl_xor(cs[j], 16, 64);  cs[j]  += __shfl_xor(cs[j], 32, 64);
    cs2[j] += __shfl_xor(cs2[j], 16, 64); cs2[j] += __shfl_xor(cs2[j], 32, 64);
  }
  if (quad == 0) {
    #pragma unroll
    for (int j = 0; j < 4; ++j) {
      atomicAdd(&cls[waveN * 64 + j * 16 + l15], cs[j]);
      atomicAdd(&cls2[waveN * 64 + j * 16 + l15], cs2[j]);
    }
  }
  __syncthreads();
  if (tid < 128) atomicAdd(&statacc[256 + bn * 128 + tid], cls[tid]);
  else           atomicAdd(&statacc[768 + bn * 128 + (tid - 128)], cls2[tid - 128]);
  // coalesced h write-back: thread t -> row t>>1, 64-col half t&1
  {
    const int rloc = tid >> 1, half = tid & 1;
    f16* crow = C + (size_t)(bm * 128 + rloc) * HDIM + bn * 128 + half * 64;
    const f16* srow = ht + rloc * HT_LD + half * 64;
    #pragma unroll
    for (int j = 0; j < 8; ++j)
      *(f16x8*)(crow + j * 8) = *(const f16x8*)(srow + j * 8);
  }
}

// ---------------- BN coefficients + diff output + W3 f16 (padded 10->16 rows) ----------------
__global__ void k_bnprep(const float* __restrict__ acc, const float* __restrict__ gamma,
                         const float* __restrict__ beta, float* __restrict__ ab,
                         const float* __restrict__ W3, f16* __restrict__ W3h,
                         float* __restrict__ diff_out) {
  const int c = threadIdx.x;                        // 512 threads
  const float inv = 1.f / 65536.f;
  float mu = acc[256 + c] * inv;
  float msq = acc[768 + c] * inv;
  float var = msq - mu * mu;
  float a = gamma[c] / sqrtf(var + 1e-5f);
  ab[c] = a;
  ab[512 + c] = beta[c] - mu * a;
  #pragma unroll
  for (int o = 0; o < 16; ++o)
    W3h[o * HDIM + c] = (o < D_OUT) ? (f16)W3[o * HDIM + c] : (f16)0.f;
  if (c == 0) {
    float s1 = 0.f, s2 = 0.f;
    for (int i = 0; i < 128; ++i) { s1 += acc[i]; s2 += acc[128 + i]; }
    diff_out[0] = s1 * (1.f / 401408.f) + s2 * (1.f / 262144.f);
  }
}

// ---------------- fold BN into qW2 (in place) + bias2 ----------------
__global__ void k_bnfold(f16* __restrict__ qW2, const float* __restrict__ ab,
                         const float* __restrict__ b2, float* __restrict__ bias2) {
  __shared__ float red[256];
  const int n = blockIdx.x, t = threadIdx.x;        // 512 blocks x 256 threads
  float partial = 0.f;
  #pragma unroll
  for (int kk = 0; kk < 2; ++kk) {
    int k = t + kk * 256;
    float w = (float)qW2[n * HDIM + k];
    partial += ab[512 + k] * w;
    qW2[n * HDIM + k] = (f16)(ab[k] * w);
  }
  red[t] = partial; __syncthreads();
  for (int s = 128; s > 0; s >>= 1) { if (t < s) red[t] += red[t + s]; __syncthreads(); }
  if (t == 0) bias2[n] = b2[n] + red[0];
}

// ---------------- GEMM2 + fused final layer ----------------
// Same dbuf single-barrier pipeline; all staging via global_load_lds (pure f16).
__global__ void __launch_bounds__(256, 4)
k_gemm2f(const f16* __restrict__ A, const f16* __restrict__ Bw,
         const float* __restrict__ bias2, const f16* __restrict__ W3h,
         const float* __restrict__ b3, float* __restrict__ out) {
  __shared__ __align__(16) char lds_all[HT_LD * 128 * 2];   // 34816 B union
  f16* ht = (f16*)lds_all;
  const int tid = threadIdx.x;
  const int logical = ((blockIdx.x & 7) << 8) + (blockIdx.x >> 3);  // XCD swizzle
  const int bn = logical & 3;
  const int bm = logical >> 2;
  const int lane = tid & 63, wid = tid >> 6;
  const int waveM = wid & 1, waveN = wid >> 1;
  const int l15 = lane & 15, quad = lane >> 4;

  const f16* gA0 = A  + (size_t)(bm * 128 + (tid >> 2)) * HDIM + (tid & 3) * 8;
  const f16* gA1 = gA0 + (size_t)64 * HDIM;
  const f16* gB0 = Bw + (size_t)(bn * 128 + (tid >> 2)) * HDIM + (tid & 3) * 8;
  const f16* gB1 = gB0 + (size_t)64 * HDIM;

  f32x4 acc[4][4];
  #pragma unroll
  for (int i = 0; i < 4; ++i)
    #pragma unroll
    for (int j = 0; j < 4; ++j) acc[i][j] = (f32x4){0.f, 0.f, 0.f, 0.f};

  const int aoff = (waveM * 64 + l15) * 32 + quad * 8;
  const int boff = (waveN * 64 + l15) * 32 + quad * 8;

  auto issueT = [&](int k0, int b) {
    f16* As_ = (f16*)(lds_all + b * 8192);
    f16* Bs_ = (f16*)(lds_all + 16384 + b * 8192);
    gld_lds16(gA0 + k0, As_ + tid * 8);
    gld_lds16(gA1 + k0, As_ + tid * 8 + 2048);
    gld_lds16(gB0 + k0, Bs_ + tid * 8);
    gld_lds16(gB1 + k0, Bs_ + tid * 8 + 2048);
  };
  auto mma = [&](const f16* A_, const f16* B_) {
    f16x8 af[4], bf[4];
    #pragma unroll
    for (int i = 0; i < 4; ++i) af[i] = *(const f16x8*)(A_ + aoff + i * 512);
    #pragma unroll
    for (int j = 0; j < 4; ++j) bf[j] = *(const f16x8*)(B_ + boff + j * 512);
    #pragma unroll
    for (int i = 0; i < 4; ++i)
      #pragma unroll
      for (int j = 0; j < 4; ++j)
        acc[i][j] = __builtin_amdgcn_mfma_f32_16x16x32_f16(af[i], bf[j], acc[i][j], 0, 0, 0);
  };

  const int NT = HDIM / 32;                // 16
  issueT(0, 0);
  asm volatile("s_waitcnt vmcnt(0)" ::: "memory");
  BARRIER();

  for (int k = 0; k < NT; ++k) {
    const int cur = k & 1;
    if (k + 1 < NT) issueT((k + 1) * 32, cur ^ 1);
    MEMFENCE;
    __builtin_amdgcn_s_setprio(1);
    mma((f16*)(lds_all + cur * 8192), (f16*)(lds_all + 16384 + cur * 8192));
    __builtin_amdgcn_s_setprio(0);
    if (k + 1 < NT) asm volatile("s_waitcnt vmcnt(0)" ::: "memory");
    BARRIER();
  }
  // epilogue: relu+bias2 -> LDS f16 tile (no global h2)
  const int colbase = bn * 128 + waveN * 64 + l15;
  float bcol[4];
  #pragma unroll
  for (int j = 0; j < 4; ++j) bcol[j] = bias2[colbase + j * 16];
  #pragma unroll
  for (int i = 0; i < 4; ++i)
    #pragma unroll
    for (int r2 = 0; r2 < 4; ++r2) {
      int rloc = waveM * 64 + quad * 4 + i * 16 + r2;
      #pragma unroll
      for (int j = 0; j < 4; ++j) {
        float v = acc[i][j][r2] + bcol[j];
        v = v > 0.f ? v : 0.f;
        ht[rloc * HT_LD + waveN * 64 + j * 16 + l15] = (f16)v;
      }
    }
  __syncthreads();
  // final layer: rows [wid*32, wid*32+32), N=16 (W3h padded), K=128 = this tile's
  // columns bn*128..bn*128+127 -> W3h columns offset by bn*128.
  f32x4 oacc[2];
  oacc[0] = (f32x4){0.f,0.f,0.f,0.f}; oacc[1] = (f32x4){0.f,0.f,0.f,0.f};
  #pragma unroll
  for (int ks = 0; ks < 4; ++ks) {
    f16x8 bfr = *(const f16x8*)(W3h + l15 * HDIM + bn * 128 + ks * 32 + quad * 8);
    #pragma unroll
    for (int i2 = 0; i2 < 2; ++i2) {
      f16x8 afr = *(const f16x8*)(ht + (wid * 32 + i2 * 16 + l15) * HT_LD + ks * 32 + quad * 8);
      oacc[i2] = __builtin_amdgcn_mfma_f32_16x16x32_f16(afr, bfr, oacc[i2], 0, 0, 0);
    }
  }
  if (l15 < D_OUT) {
    float badd = (bn == 0) ? b3[l15] : 0.f;
    #pragma unroll
    for (int i2 = 0; i2 < 2; ++i2)
      #pragma unroll
      for (int r2 = 0; r2 < 4; ++r2) {
        int row = bm * 128 + wid * 32 + i2 * 16 + quad * 4 + r2;
        atomicAdd(&out[(size_t)row * D_OUT + l15], oacc[i2][r2] + badd);
      }
  }
}

extern "C" void kernel_launch(void* const* d_in, const int* in_sizes, int n_in,
                              void* d_out, int out_size, void* d_ws, size_t ws_size,
                              hipStream_t stream) {
  const float* x     = (const float*)d_in[0];
  const float* W1    = (const float*)d_in[1];
  const float* b1    = (const float*)d_in[2];
  const float* gamma = (const float*)d_in[3];
  const float* beta  = (const float*)d_in[4];
  const float* E1    = (const float*)d_in[5];
  const float* W2    = (const float*)d_in[6];
  const float* b2    = (const float*)d_in[7];
  const float* E2    = (const float*)d_in[8];
  const float* W3    = (const float*)d_in[9];
  const float* b3    = (const float*)d_in[10];
  float* out = (float*)d_out;

  char* ws = (char*)d_ws;
  float* accum = (float*)ws;                       // [0,128) diff1, [128,256) diff2, [256,768) colsum, [768,1280) colsumsq
  f16* qW1h = (f16*)(ws + 8192);                   // 512*800*2 = 819200
  f16* qW2h = (f16*)(ws + 827392);                 // 512*512*2 = 524288
  f16* W3h  = (f16*)(ws + 1351680);                // 16*512*2  = 16384
  float* ab = (float*)(ws + 1368064);              // 1024*4
  float* bias2 = (float*)(ws + 1372160);           // 512*4
  f16* h    = (f16*)(ws + 1376256);                // 65536*512*2 = 67108864

  hipMemsetAsync(ws, 0, 827392, stream);           // accum + qW1h (zero K-padding)
  hipMemsetAsync(d_out, 0, (size_t)out_size * 4, stream);  // out accumulated via atomics
  k_vq1<<<3584, 256, 0, stream>>>(W1, E1, qW1h, accum);
  k_vq2<<<4096, 256, 0, stream>>>(W2, E2, qW2h, accum + 128);
  k_gemm1<<<2048, 256, 0, stream>>>(x, qW1h, b1, h, accum);
  k_bnprep<<<1, 512, 0, stream>>>(accum, gamma, beta, ab, W3, W3h, out + (size_t)BATCH * D_OUT);
  k_bnfold<<<512, 256, 0, stream>>>(qW2h, ab, b2, bias2);
  k_gemm2f<<<2048, 256, 0, stream>>>(h, qW2h, bias2, W3h, b3, out);
}

// Round 4
// 516.553 us; speedup vs baseline: 1.1625x; 1.0569x over previous
//
#include <hip/hip_runtime.h>
#include <stdint.h>

// Sizes (fixed by the problem)
#define BATCH   65536
#define D_IN    784
#define KP      800      // D_IN padded to a multiple of BK=32
#define HDIM    512
#define D_OUT   10
#define NCODE   512
#define HT_LD   520      // epilogue LDS tile leading dim (512 + 8 f16 pad)

typedef _Float16 f16;
typedef _Float16 f16x8 __attribute__((ext_vector_type(8)));
typedef float    f32x4 __attribute__((ext_vector_type(4)));

__device__ __forceinline__ void gld_lds16(const void* g, void* l) {
  __builtin_amdgcn_global_load_lds((const __attribute__((address_space(1))) void*)g,
                                   (__attribute__((address_space(3))) void*)l, 16, 0, 0);
}

#define MEMFENCE asm volatile("" ::: "memory")
#define BARRIER() do { MEMFENCE; __builtin_amdgcn_s_barrier(); MEMFENCE; } while (0)

// ---------------- VQ W1: blocks (og<128, ig<112), dim 28 ----------------
// Replicates numpy-fp32 semantics (verified: absmax 0.0156).
__global__ void k_vq1(const float* __restrict__ W1, const float* __restrict__ E1,
                      f16* __restrict__ qW1, float* __restrict__ diffacc) {
  #pragma clang fp contract(off)
  __shared__ float E1s[28 * NCODE];
  __shared__ float Ts[NCODE];
  for (int i = threadIdx.x; i < 28 * NCODE; i += 256) E1s[i] = E1[i];
  __syncthreads();
  for (int k = threadIdx.x; k < NCODE; k += 256) {
    float e0 = E1s[k];
    float t = e0 * e0;
    for (int j = 1; j < 28; ++j) {
      float e = E1s[j * NCODE + k];
      float ee = e * e;
      t = t + ee;
    }
    Ts[k] = t;
  }
  __syncthreads();
  const int wid = threadIdx.x >> 6, lane = threadIdx.x & 63;
  const int bid = blockIdx.x * 4 + wid;          // < 14336
  const int og = bid / 112, ig = bid % 112;
  float v[28], vv[28];
  #pragma unroll
  for (int j = 0; j < 28; ++j) {
    int om = j & 3, im = j >> 2;
    v[j] = W1[(og * 4 + om) * D_IN + ig * 7 + im];
    vv[j] = v[j] * v[j];
  }
  float r[8];
  #pragma unroll
  for (int j = 0; j < 8; ++j) r[j] = vv[j];
  #pragma unroll
  for (int j = 0; j < 8; ++j) r[j] = r[j] + vv[8 + j];
  #pragma unroll
  for (int j = 0; j < 8; ++j) r[j] = r[j] + vv[16 + j];
  float s = ((r[0] + r[1]) + (r[2] + r[3])) + ((r[4] + r[5]) + (r[6] + r[7]));
  s = s + vv[24]; s = s + vv[25]; s = s + vv[26]; s = s + vv[27];

  float bestd = 1e30f; int bestk = 0x7fffffff;
  for (int t = 0; t < 8; ++t) {
    int k = t * 64 + lane;
    float dot = 0.f;
    #pragma unroll
    for (int j = 0; j < 28; ++j) dot = __builtin_fmaf(v[j], E1s[j * NCODE + k], dot);
    float d = (s - 2.0f * dot) + Ts[k];
    if (d < bestd || (d == bestd && k < bestk)) { bestd = d; bestk = k; }
  }
  for (int off = 32; off; off >>= 1) {
    float d2 = __shfl_down(bestd, off, 64);
    int   k2 = __shfl_down(bestk, off, 64);
    if (d2 < bestd || (d2 == bestd && k2 < bestk)) { bestd = d2; bestk = k2; }
  }
  int kstar = __shfl(bestk, 0, 64);
  float sq = 0.f;
  if (lane < 28) {
    int om = lane & 3, im = lane >> 2;
    float q = E1s[lane * NCODE + kstar];
    qW1[(size_t)(og * 4 + om) * KP + ig * 7 + im] = (f16)q;
    float dd = q - v[lane]; sq = dd * dd;
  }
  for (int off = 32; off; off >>= 1) sq += __shfl_down(sq, off, 64);
  if (lane == 0) atomicAdd(&diffacc[bid & 127], sq);
}

// ---------------- VQ W2: blocks (og<512, ig<32), dim 16 contiguous ----------------
__global__ void k_vq2(const float* __restrict__ W2, const float* __restrict__ E2,
                      f16* __restrict__ qW2, float* __restrict__ diffacc) {
  #pragma clang fp contract(off)
  __shared__ float E2s[16 * NCODE];
  __shared__ float Ts[NCODE];
  for (int i = threadIdx.x; i < 16 * NCODE; i += 256) E2s[i] = E2[i];
  __syncthreads();
  for (int k = threadIdx.x; k < NCODE; k += 256) {
    float e0 = E2s[k];
    float t = e0 * e0;
    for (int j = 1; j < 16; ++j) {
      float e = E2s[j * NCODE + k];
      float ee = e * e;
      t = t + ee;
    }
    Ts[k] = t;
  }
  __syncthreads();
  const int wid = threadIdx.x >> 6, lane = threadIdx.x & 63;
  const int bid = blockIdx.x * 4 + wid;          // < 16384
  const int og = bid >> 5, ig = bid & 31;
  float v[16], vv[16];
  #pragma unroll
  for (int j = 0; j < 16; ++j) {
    v[j] = W2[og * HDIM + ig * 16 + j];
    vv[j] = v[j] * v[j];
  }
  float r[8];
  #pragma unroll
  for (int j = 0; j < 8; ++j) r[j] = vv[j];
  #pragma unroll
  for (int j = 0; j < 8; ++j) r[j] = r[j] + vv[8 + j];
  float s = ((r[0] + r[1]) + (r[2] + r[3])) + ((r[4] + r[5]) + (r[6] + r[7]));

  float bestd = 1e30f; int bestk = 0x7fffffff;
  for (int t = 0; t < 8; ++t) {
    int k = t * 64 + lane;
    float dot = 0.f;
    #pragma unroll
    for (int j = 0; j < 16; ++j) dot = __builtin_fmaf(v[j], E2s[j * NCODE + k], dot);
    float d = (s - 2.0f * dot) + Ts[k];
    if (d < bestd || (d == bestd && k < bestk)) { bestd = d; bestk = k; }
  }
  for (int off = 32; off; off >>= 1) {
    float d2 = __shfl_down(bestd, off, 64);
    int   k2 = __shfl_down(bestk, off, 64);
    if (d2 < bestd || (d2 == bestd && k2 < bestk)) { bestd = d2; bestk = k2; }
  }
  int kstar = __shfl(bestk, 0, 64);
  float sq = 0.f;
  if (lane < 16) {
    float q = E2s[lane * NCODE + kstar];
    qW2[(size_t)og * HDIM + ig * 16 + lane] = (f16)q;
    float dd = q - v[lane]; sq = dd * dd;
  }
  for (int off = 32; off; off >>= 1) sq += __shfl_down(sq, off, 64);
  if (lane == 0) atomicAdd(&diffacc[bid & 127], sq);
}

// ---------------- GEMM1: h = relu(x @ qW1^T + b1), fused cvt + column stats ----------
// 512 threads, tile 128x512 (full N): wave tile 64x128 (acc 4x8) doubles the
// FLOP/LDS-byte intensity (the R2 ceiling). Triple-buffered staging (3x40KB,
// tracked as BYTE OFFSETS -- no LDS pointer arrays, R3 compile fix), one
// barrier per K-step, counted vmcnt (loads never drain). Chunk swizzle
// c' = c ^ ((row>>1)&3) kills the 8-way fragment-read bank conflict.
__global__ void __launch_bounds__(512, 2)
k_gemm1(const float* __restrict__ X, const f16* __restrict__ Bw,
        const float* __restrict__ bias, f16* __restrict__ C,
        float* __restrict__ statacc) {
  __shared__ __align__(16) char lds_all[HT_LD * 128 * 2];   // 133120 B union (>= 3x40960 staging)
  __shared__ float cls[512], cls2[512];
  f16* ht = (f16*)lds_all;
  const int tid = threadIdx.x;
  const int bm = blockIdx.x;                      // 512 blocks, rows owned exclusively
  const int lane = tid & 63, wid = tid >> 6;
  const int waveM = wid & 1, waveN = wid >> 1;    // 2M x 4N waves
  const int l15 = lane & 15, quad = lane >> 4;

  cls[tid] = 0.f; cls2[tid] = 0.f;

  // A staging: thread t owns slot (row=t>>2, c=t&3) of the 128x32 f16 tile.
  const int rA = tid >> 2, cA = tid & 3;
  const float* gArow = X + (size_t)(bm * 128 + rA) * D_IN;
  const int wAoff = rA * 32 + ((cA ^ ((rA >> 1) & 3)) * 8);   // swizzled LDS chunk
  // B staging: 4 slots/thread of the 512x32 f16 tile; linear LDS dest
  // (global_load_lds), source chunk pre-swizzled.
  const f16* gBp[4]; int lBoff[4];
  #pragma unroll
  for (int i = 0; i < 4; ++i) {
    int s = tid + i * 512;
    int rB = s >> 2, cB = s & 3;
    gBp[i] = Bw + (size_t)rB * KP + ((cB ^ ((rB >> 1) & 3)) * 8);
    lBoff[i] = s * 8;
  }

  f32x4 acc[4][8];
  #pragma unroll
  for (int i = 0; i < 4; ++i)
    #pragma unroll
    for (int j = 0; j < 8; ++j) acc[i][j] = (f32x4){0.f, 0.f, 0.f, 0.f};

  const int cs_l = (l15 >> 1) & 3;
  const int aoff = (waveM * 64 + l15) * 32;
  const int boff = (waveN * 128 + l15) * 32;
  const int qoff = (quad ^ cs_l) * 8;

  float4 ra0, ra1;
  auto issueA = [&](int k0) {
    int gc = k0 + cA * 8;
    int gco = gc < D_IN ? gc : 0;     // clamp: always 2 loads (vmcnt determinism)
    ra0 = *(const float4*)(gArow + gco);
    ra1 = *(const float4*)(gArow + gco + 4);
  };
  auto writeA = [&](int k0, char* buf) {
    float4 a0 = ra0, a1 = ra1;
    if (k0 + cA * 8 >= D_IN) { a0 = (float4){0.f,0.f,0.f,0.f}; a1 = a0; }
    f16x8 o;
    o[0]=(f16)a0.x; o[1]=(f16)a0.y; o[2]=(f16)a0.z; o[3]=(f16)a0.w;
    o[4]=(f16)a1.x; o[5]=(f16)a1.y; o[6]=(f16)a1.z; o[7]=(f16)a1.w;
    *(f16x8*)((f16*)buf + wAoff) = o;
  };
  auto issueB = [&](int k0, char* buf) {
    f16* Bs_ = (f16*)(buf + 8192);
    #pragma unroll
    for (int i = 0; i < 4; ++i) gld_lds16(gBp[i] + k0, Bs_ + lBoff[i]);
  };
  auto mma = [&](const char* buf) {
    const f16* As_ = (const f16*)buf;
    const f16* Bs_ = (const f16*)(buf + 8192);
    f16x8 af[4], bf[8];
    #pragma unroll
    for (int i = 0; i < 4; ++i) af[i] = *(const f16x8*)(As_ + aoff + i * 512 + qoff);
    #pragma unroll
    for (int j = 0; j < 8; ++j) bf[j] = *(const f16x8*)(Bs_ + boff + j * 512 + qoff);
    #pragma unroll
    for (int i = 0; i < 4; ++i)
      #pragma unroll
      for (int j = 0; j < 8; ++j)
        acc[i][j] = __builtin_amdgcn_mfma_f32_16x16x32_f16(af[i], bf[j], acc[i][j], 0, 0, 0);
  };

  const int NT = KP / 32;                   // 25

  // prologue: queue = A0(2) B0(4) B1(4) A1(2)
  issueA(0);  MEMFENCE;
  issueB(0, lds_all);          MEMFENCE;
  issueB(32, lds_all + 40960); MEMFENCE;
  writeA(0, lds_all);                       // implicit wait A0
  MEMFENCE;
  issueA(32); MEMFENCE;
  asm volatile("s_waitcnt vmcnt(6) lgkmcnt(0)" ::: "memory");   // B0 landed
  BARRIER();

  int cur = 0;                              // byte offset of current buffer
  for (int k = 0; k < NT; ++k) {
    int n1 = cur + 40960; if (n1 == 122880) n1 = 0;
    int n2 = n1 + 40960;  if (n2 == 122880) n2 = 0;
    if (k + 2 < NT) { issueB((k + 2) * 32, lds_all + n2); }
    MEMFENCE;
    __builtin_amdgcn_s_setprio(1);
    mma(lds_all + cur);
    __builtin_amdgcn_s_setprio(0);
    if (k + 1 < NT) {
      MEMFENCE;
      writeA((k + 1) * 32, lds_all + n1);   // implicit reg-wait on A(k+1)
      MEMFENCE;
      if (k + 2 < NT) {
        issueA((k + 2) * 32); MEMFENCE;
        asm volatile("s_waitcnt vmcnt(6) lgkmcnt(0)" ::: "memory");
      } else {
        asm volatile("s_waitcnt vmcnt(0) lgkmcnt(0)" ::: "memory");
      }
    }
    BARRIER();
    cur = n1;
  }

  // epilogue: relu+bias -> ht (f16) + per-column stats on fp32 values
  const int colbase = waveN * 128 + l15;
  float bcol[8];
  #pragma unroll
  for (int j = 0; j < 8; ++j) bcol[j] = bias[colbase + j * 16];
  float cs[8], cs2[8];
  #pragma unroll
  for (int j = 0; j < 8; ++j) { cs[j] = 0.f; cs2[j] = 0.f; }
  #pragma unroll
  for (int i = 0; i < 4; ++i)
    #pragma unroll
    for (int r2 = 0; r2 < 4; ++r2) {
      int rloc = waveM * 64 + i * 16 + quad * 4 + r2;
      #pragma unroll
      for (int j = 0; j < 8; ++j) {
        float v = acc[i][j][r2] + bcol[j];
        v = v > 0.f ? v : 0.f;
        ht[rloc * HT_LD + waveN * 128 + j * 16 + l15] = (f16)v;
        cs[j] += v; cs2[j] += v * v;
      }
    }
  #pragma unroll
  for (int j = 0; j < 8; ++j) {
    cs[j]  += __shfl_xor(cs[j], 16, 64);  cs[j]  += __shfl_xor(cs[j], 32, 64);
    cs2[j] += __shfl_xor(cs2[j], 16, 64); cs2[j] += __shfl_xor(cs2[j], 32, 64);
  }
  if (quad == 0) {
    #pragma unroll
    for (int j = 0; j < 8; ++j) {
      atomicAdd(&cls[waveN * 128 + j * 16 + l15], cs[j]);
      atomicAdd(&cls2[waveN * 128 + j * 16 + l15], cs2[j]);
    }
  }
  __syncthreads();
  atomicAdd(&statacc[256 + tid], cls[tid]);
  atomicAdd(&statacc[768 + tid], cls2[tid]);
  // coalesced h write-back: wave w -> rows w*16..w*16+15; one 1KB row per store
  #pragma unroll
  for (int rr = 0; rr < 16; ++rr) {
    int row = wid * 16 + rr;
    f16x8 vrow = *(const f16x8*)(ht + row * HT_LD + lane * 8);
    *(f16x8*)(C + (size_t)(bm * 128 + row) * HDIM + lane * 8) = vrow;
  }
}

// ---------------- BN coefficients + diff output + W3 f16 (padded 10->16 rows) ----------------
__global__ void k_bnprep(const float* __restrict__ acc, const float* __restrict__ gamma,
                         const float* __restrict__ beta, float* __restrict__ ab,
                         const float* __restrict__ W3, f16* __restrict__ W3h,
                         float* __restrict__ diff_out) {
  const int c = threadIdx.x;                        // 512 threads
  const float inv = 1.f / 65536.f;
  float mu = acc[256 + c] * inv;
  float msq = acc[768 + c] * inv;
  float var = msq - mu * mu;
  float a = gamma[c] / sqrtf(var + 1e-5f);
  ab[c] = a;
  ab[512 + c] = beta[c] - mu * a;
  #pragma unroll
  for (int o = 0; o < 16; ++o)
    W3h[o * HDIM + c] = (o < D_OUT) ? (f16)W3[o * HDIM + c] : (f16)0.f;
  if (c == 0) {
    float s1 = 0.f, s2 = 0.f;
    for (int i = 0; i < 128; ++i) { s1 += acc[i]; s2 += acc[128 + i]; }
    diff_out[0] = s1 * (1.f / 401408.f) + s2 * (1.f / 262144.f);
  }
}

// ---------------- fold BN into qW2 (in place) + bias2 ----------------
__global__ void k_bnfold(f16* __restrict__ qW2, const float* __restrict__ ab,
                         const float* __restrict__ b2, float* __restrict__ bias2) {
  __shared__ float red[256];
  const int n = blockIdx.x, t = threadIdx.x;        // 512 blocks x 256 threads
  float partial = 0.f;
  #pragma unroll
  for (int kk = 0; kk < 2; ++kk) {
    int k = t + kk * 256;
    float w = (float)qW2[n * HDIM + k];
    partial += ab[512 + k] * w;
    qW2[n * HDIM + k] = (f16)(ab[k] * w);
  }
  red[t] = partial; __syncthreads();
  for (int s = 128; s > 0; s >>= 1) { if (t < s) red[t] += red[t + s]; __syncthreads(); }
  if (t == 0) bias2[n] = b2[n] + red[0];
}

// ---------------- GEMM2 + fused final layer ----------------
// Same 128x512 full-N structure. All staging via global_load_lds (5/thread),
// triple-buffered (byte-offset tracked), counted vmcnt(5). Final layer has
// full K=512 in-block -> direct out stores (no atomics, no memset).
__global__ void __launch_bounds__(512, 2)
k_gemm2f(const f16* __restrict__ A, const f16* __restrict__ Bw,
         const float* __restrict__ bias2, const f16* __restrict__ W3h,
         const float* __restrict__ b3, float* __restrict__ out) {
  __shared__ __align__(16) char lds_all[HT_LD * 128 * 2];   // 133120 B union
  f16* ht = (f16*)lds_all;
  const int tid = threadIdx.x;
  const int bm = blockIdx.x;
  const int lane = tid & 63, wid = tid >> 6;
  const int waveM = wid & 1, waveN = wid >> 1;
  const int l15 = lane & 15, quad = lane >> 4;

  // A staging: 1 slot/thread (128x32 f16); B: 4 slots/thread (512x32 f16).
  const int rA = tid >> 2, cA = tid & 3;
  const f16* gAp = A + (size_t)(bm * 128 + rA) * HDIM + ((cA ^ ((rA >> 1) & 3)) * 8);
  const int lAoff = tid * 8;
  const f16* gBp[4]; int lBoff[4];
  #pragma unroll
  for (int i = 0; i < 4; ++i) {
    int s = tid + i * 512;
    int rB = s >> 2, cB = s & 3;
    gBp[i] = Bw + (size_t)rB * HDIM + ((cB ^ ((rB >> 1) & 3)) * 8);
    lBoff[i] = s * 8;
  }

  f32x4 acc[4][8];
  #pragma unroll
  for (int i = 0; i < 4; ++i)
    #pragma unroll
    for (int j = 0; j < 8; ++j) acc[i][j] = (f32x4){0.f, 0.f, 0.f, 0.f};

  const int cs_l = (l15 >> 1) & 3;
  const int aoff = (waveM * 64 + l15) * 32;
  const int boff = (waveN * 128 + l15) * 32;
  const int qoff = (quad ^ cs_l) * 8;

  auto issueT = [&](int k0, char* buf) {
    f16* As_ = (f16*)buf;
    f16* Bs_ = (f16*)(buf + 8192);
    gld_lds16(gAp + k0, As_ + lAoff);
    #pragma unroll
    for (int i = 0; i < 4; ++i) gld_lds16(gBp[i] + k0, Bs_ + lBoff[i]);
  };
  auto mma = [&](const char* buf) {
    const f16* As_ = (const f16*)buf;
    const f16* Bs_ = (const f16*)(buf + 8192);
    f16x8 af[4], bf[8];
    #pragma unroll
    for (int i = 0; i < 4; ++i) af[i] = *(const f16x8*)(As_ + aoff + i * 512 + qoff);
    #pragma unroll
    for (int j = 0; j < 8; ++j) bf[j] = *(const f16x8*)(Bs_ + boff + j * 512 + qoff);
    #pragma unroll
    for (int i = 0; i < 4; ++i)
      #pragma unroll
      for (int j = 0; j < 8; ++j)
        acc[i][j] = __builtin_amdgcn_mfma_f32_16x16x32_f16(af[i], bf[j], acc[i][j], 0, 0, 0);
  };

  const int NT = HDIM / 32;                 // 16

  issueT(0, lds_all);          MEMFENCE;
  issueT(32, lds_all + 40960); MEMFENCE;
  asm volatile("s_waitcnt vmcnt(5)" ::: "memory");   // T(0) landed, T(1) in flight
  BARRIER();

  int cur = 0;
  for (int k = 0; k < NT; ++k) {
    int n1 = cur + 40960; if (n1 == 122880) n1 = 0;
    int n2 = n1 + 40960;  if (n2 == 122880) n2 = 0;
    if (k + 2 < NT) { issueT((k + 2) * 32, lds_all + n2); }
    MEMFENCE;
    __builtin_amdgcn_s_setprio(1);
    mma(lds_all + cur);
    __builtin_amdgcn_s_setprio(0);
    if (k + 2 < NT)      asm volatile("s_waitcnt vmcnt(5)" ::: "memory");
    else if (k + 1 < NT) asm volatile("s_waitcnt vmcnt(0)" ::: "memory");
    BARRIER();
    cur = n1;
  }

  // epilogue: relu+bias2 -> ht (f16)
  const int colbase = waveN * 128 + l15;
  float bcol[8];
  #pragma unroll
  for (int j = 0; j < 8; ++j) bcol[j] = bias2[colbase + j * 16];
  #pragma unroll
  for (int i = 0; i < 4; ++i)
    #pragma unroll
    for (int r2 = 0; r2 < 4; ++r2) {
      int rloc = waveM * 64 + i * 16 + quad * 4 + r2;
      #pragma unroll
      for (int j = 0; j < 8; ++j) {
        float v = acc[i][j][r2] + bcol[j];
        v = v > 0.f ? v : 0.f;
        ht[rloc * HT_LD + waveN * 128 + j * 16 + l15] = (f16)v;
      }
    }
  __syncthreads();
  // final layer: wave w -> rows w*16..w*16+15; full K=512 in-block; direct store.
  f32x4 oacc = (f32x4){0.f, 0.f, 0.f, 0.f};
  #pragma unroll
  for (int ks = 0; ks < 16; ++ks) {
    f16x8 bfr = *(const f16x8*)(W3h + l15 * HDIM + ks * 32 + quad * 8);
    f16x8 afr = *(const f16x8*)(ht + (wid * 16 + l15) * HT_LD + ks * 32 + quad * 8);
    oacc = __builtin_amdgcn_mfma_f32_16x16x32_f16(afr, bfr, oacc, 0, 0, 0);
  }
  if (l15 < D_OUT) {
    float badd = b3[l15];
    #pragma unroll
    for (int r2 = 0; r2 < 4; ++r2) {
      int row = bm * 128 + wid * 16 + quad * 4 + r2;
      out[(size_t)row * D_OUT + l15] = oacc[r2] + badd;
    }
  }
}

extern "C" void kernel_launch(void* const* d_in, const int* in_sizes, int n_in,
                              void* d_out, int out_size, void* d_ws, size_t ws_size,
                              hipStream_t stream) {
  const float* x     = (const float*)d_in[0];
  const float* W1    = (const float*)d_in[1];
  const float* b1    = (const float*)d_in[2];
  const float* gamma = (const float*)d_in[3];
  const float* beta  = (const float*)d_in[4];
  const float* E1    = (const float*)d_in[5];
  const float* W2    = (const float*)d_in[6];
  const float* b2    = (const float*)d_in[7];
  const float* E2    = (const float*)d_in[8];
  const float* W3    = (const float*)d_in[9];
  const float* b3    = (const float*)d_in[10];
  float* out = (float*)d_out;

  char* ws = (char*)d_ws;
  float* accum = (float*)ws;                       // [0,128) diff1, [128,256) diff2, [256,768) colsum, [768,1280) colsumsq
  f16* qW1h = (f16*)(ws + 8192);                   // 512*800*2 = 819200
  f16* qW2h = (f16*)(ws + 827392);                 // 512*512*2 = 524288
  f16* W3h  = (f16*)(ws + 1351680);                // 16*512*2  = 16384
  float* ab = (float*)(ws + 1368064);              // 1024*4
  float* bias2 = (float*)(ws + 1372160);           // 512*4
  f16* h    = (f16*)(ws + 1376256);                // 65536*512*2 = 67108864

  (void)hipMemsetAsync(ws, 0, 827392, stream);     // accum + qW1h (zero K-padding)
  k_vq1<<<3584, 256, 0, stream>>>(W1, E1, qW1h, accum);
  k_vq2<<<4096, 256, 0, stream>>>(W2, E2, qW2h, accum + 128);
  k_gemm1<<<512, 512, 0, stream>>>(x, qW1h, b1, h, accum);
  k_bnprep<<<1, 512, 0, stream>>>(accum, gamma, beta, ab, W3, W3h, out + (size_t)BATCH * D_OUT);
  k_bnfold<<<512, 256, 0, stream>>>(qW2h, ab, b2, bias2);
  k_gemm2f<<<512, 512, 0, stream>>>(h, qW2h, bias2, W3h, b3, out);
}

// Round 5
// 515.115 us; speedup vs baseline: 1.1658x; 1.0028x over previous
//
#include <hip/hip_runtime.h>
#include <stdint.h>

// Sizes (fixed by the problem)
#define BATCH   65536
#define D_IN    784
#define KP      832      // D_IN padded to a multiple of BK=64
#define HDIM    512
#define D_OUT   10
#define NCODE   512
#define HT_LD   520      // epilogue LDS tile leading dim (512 + 8 f16 pad)

typedef _Float16 f16;
typedef _Float16 f16x8 __attribute__((ext_vector_type(8)));
typedef float    f32x4 __attribute__((ext_vector_type(4)));

__device__ __forceinline__ void gld_lds16(const void* g, void* l) {
  __builtin_amdgcn_global_load_lds((const __attribute__((address_space(1))) void*)g,
                                   (__attribute__((address_space(3))) void*)l, 16, 0, 0);
}

#define MEMFENCE asm volatile("" ::: "memory")
#define BARRIER() do { MEMFENCE; __builtin_amdgcn_s_barrier(); MEMFENCE; } while (0)

// ---------------- VQ W1: blocks (og<128, ig<112), dim 28 ----------------
// Replicates numpy-fp32 semantics (verified: absmax 0.0156).
__global__ void k_vq1(const float* __restrict__ W1, const float* __restrict__ E1,
                      f16* __restrict__ qW1, float* __restrict__ diffacc) {
  #pragma clang fp contract(off)
  __shared__ float E1s[28 * NCODE];
  __shared__ float Ts[NCODE];
  for (int i = threadIdx.x; i < 28 * NCODE; i += 256) E1s[i] = E1[i];
  __syncthreads();
  for (int k = threadIdx.x; k < NCODE; k += 256) {
    float e0 = E1s[k];
    float t = e0 * e0;
    for (int j = 1; j < 28; ++j) {
      float e = E1s[j * NCODE + k];
      float ee = e * e;
      t = t + ee;
    }
    Ts[k] = t;
  }
  __syncthreads();
  const int wid = threadIdx.x >> 6, lane = threadIdx.x & 63;
  const int bid = blockIdx.x * 4 + wid;          // < 14336
  const int og = bid / 112, ig = bid % 112;
  float v[28], vv[28];
  #pragma unroll
  for (int j = 0; j < 28; ++j) {
    int om = j & 3, im = j >> 2;
    v[j] = W1[(og * 4 + om) * D_IN + ig * 7 + im];
    vv[j] = v[j] * v[j];
  }
  float r[8];
  #pragma unroll
  for (int j = 0; j < 8; ++j) r[j] = vv[j];
  #pragma unroll
  for (int j = 0; j < 8; ++j) r[j] = r[j] + vv[8 + j];
  #pragma unroll
  for (int j = 0; j < 8; ++j) r[j] = r[j] + vv[16 + j];
  float s = ((r[0] + r[1]) + (r[2] + r[3])) + ((r[4] + r[5]) + (r[6] + r[7]));
  s = s + vv[24]; s = s + vv[25]; s = s + vv[26]; s = s + vv[27];

  float bestd = 1e30f; int bestk = 0x7fffffff;
  for (int t = 0; t < 8; ++t) {
    int k = t * 64 + lane;
    float dot = 0.f;
    #pragma unroll
    for (int j = 0; j < 28; ++j) dot = __builtin_fmaf(v[j], E1s[j * NCODE + k], dot);
    float d = (s - 2.0f * dot) + Ts[k];
    if (d < bestd || (d == bestd && k < bestk)) { bestd = d; bestk = k; }
  }
  for (int off = 32; off; off >>= 1) {
    float d2 = __shfl_down(bestd, off, 64);
    int   k2 = __shfl_down(bestk, off, 64);
    if (d2 < bestd || (d2 == bestd && k2 < bestk)) { bestd = d2; bestk = k2; }
  }
  int kstar = __shfl(bestk, 0, 64);
  float sq = 0.f;
  if (lane < 28) {
    int om = lane & 3, im = lane >> 2;
    float q = E1s[lane * NCODE + kstar];
    qW1[(size_t)(og * 4 + om) * KP + ig * 7 + im] = (f16)q;
    float dd = q - v[lane]; sq = dd * dd;
  }
  for (int off = 32; off; off >>= 1) sq += __shfl_down(sq, off, 64);
  if (lane == 0) atomicAdd(&diffacc[bid & 127], sq);
}

// ---------------- VQ W2: blocks (og<512, ig<32), dim 16 contiguous ----------------
__global__ void k_vq2(const float* __restrict__ W2, const float* __restrict__ E2,
                      f16* __restrict__ qW2, float* __restrict__ diffacc) {
  #pragma clang fp contract(off)
  __shared__ float E2s[16 * NCODE];
  __shared__ float Ts[NCODE];
  for (int i = threadIdx.x; i < 16 * NCODE; i += 256) E2s[i] = E2[i];
  __syncthreads();
  for (int k = threadIdx.x; k < NCODE; k += 256) {
    float e0 = E2s[k];
    float t = e0 * e0;
    for (int j = 1; j < 16; ++j) {
      float e = E2s[j * NCODE + k];
      float ee = e * e;
      t = t + ee;
    }
    Ts[k] = t;
  }
  __syncthreads();
  const int wid = threadIdx.x >> 6, lane = threadIdx.x & 63;
  const int bid = blockIdx.x * 4 + wid;          // < 16384
  const int og = bid >> 5, ig = bid & 31;
  float v[16], vv[16];
  #pragma unroll
  for (int j = 0; j < 16; ++j) {
    v[j] = W2[og * HDIM + ig * 16 + j];
    vv[j] = v[j] * v[j];
  }
  float r[8];
  #pragma unroll
  for (int j = 0; j < 8; ++j) r[j] = vv[j];
  #pragma unroll
  for (int j = 0; j < 8; ++j) r[j] = r[j] + vv[8 + j];
  float s = ((r[0] + r[1]) + (r[2] + r[3])) + ((r[4] + r[5]) + (r[6] + r[7]));

  float bestd = 1e30f; int bestk = 0x7fffffff;
  for (int t = 0; t < 8; ++t) {
    int k = t * 64 + lane;
    float dot = 0.f;
    #pragma unroll
    for (int j = 0; j < 16; ++j) dot = __builtin_fmaf(v[j], E2s[j * NCODE + k], dot);
    float d = (s - 2.0f * dot) + Ts[k];
    if (d < bestd || (d == bestd && k < bestk)) { bestd = d; bestk = k; }
  }
  for (int off = 32; off; off >>= 1) {
    float d2 = __shfl_down(bestd, off, 64);
    int   k2 = __shfl_down(bestk, off, 64);
    if (d2 < bestd || (d2 == bestd && k2 < bestk)) { bestd = d2; bestk = k2; }
  }
  int kstar = __shfl(bestk, 0, 64);
  float sq = 0.f;
  if (lane < 16) {
    float q = E2s[lane * NCODE + kstar];
    qW2[(size_t)og * HDIM + ig * 16 + lane] = (f16)q;
    float dd = q - v[lane]; sq = dd * dd;
  }
  for (int off = 32; off; off >>= 1) sq += __shfl_down(sq, off, 64);
  if (lane == 0) atomicAdd(&diffacc[bid & 127], sq);
}

// ---------------- GEMM1: h = relu(x @ qW1^T + b1), fused cvt + column stats ----------
// BK=64 (13 iters, was 25): the R4 lesson is per-iteration latency is ~constant,
// so maximize FLOP/iteration. A single-buffered (16 KB, reg-staged cvt),
// B double-buffered (2x64 KB) = 147 KB LDS. Two barriers per iter; fully
// counted vmcnt (12 loads in flight at every wait; B has a full iteration of
// latency coverage). Chunk swizzle c^ = c ^ (row&7) on 64-col rows: 8 groups x
// 8 lanes = uniform 2 lanes/bank (conflict-free, same argument as R4's 0-count).
// vmcnt ledger (steady iter k):
//   top: A(k)x4 + B(k)x8 out.  writeA(k): implicit vmcnt(8) (A oldest).
//   issue A(k+1)x4, B(k+1)x8 -> 20.  explicit vmcnt(12): B(k) landed,
//   A(k+1)+B(k+1)=12 stay in flight across both barriers.
__global__ void __launch_bounds__(512, 2)
k_gemm1(const float* __restrict__ X, const f16* __restrict__ Bw,
        const float* __restrict__ bias, f16* __restrict__ C,
        float* __restrict__ statacc) {
  __shared__ __align__(16) char lds_all[147456];  // A 16K | Bst0 64K | Bst1 64K ; epi ht 133K
  __shared__ float cls[512], cls2[512];
  f16* ht = (f16*)lds_all;
  const int tid = threadIdx.x;
  const int bm = blockIdx.x;                      // 512 blocks, rows owned exclusively
  const int lane = tid & 63, wid = tid >> 6;
  const int waveM = wid & 1, waveN = wid >> 1;    // 2M x 4N waves
  const int l15 = lane & 15, quad = lane >> 4;

  cls[tid] = 0.f; cls2[tid] = 0.f;

  // A staging: thread owns row rA = tid>>2, chunks {cA, cA+4} of the 128x64 tile.
  const int rA = tid >> 2, cA = tid & 3;
  const float* gArow = X + (size_t)(bm * 128 + rA) * D_IN;
  const int wA0 = rA * 64 + ((cA ^ (rA & 7)) * 8);          // swizzled chunk slots
  const int wA1 = rA * 64 + (((cA + 4) ^ (rA & 7)) * 8);
  // B staging: 8 slots/thread of the 512x64 tile; linear LDS dest, source
  // chunk pre-swizzled (both-sides swizzle, G21).
  const f16* gBp[8]; int lBoff[8];
  #pragma unroll
  for (int i = 0; i < 8; ++i) {
    int s = tid + i * 512;
    int rB = s >> 3, cB = s & 7;
    gBp[i] = Bw + (size_t)rB * KP + ((cB ^ (rB & 7)) * 8);
    lBoff[i] = s * 8;
  }

  f32x4 acc[4][8];
  #pragma unroll
  for (int i = 0; i < 4; ++i)
    #pragma unroll
    for (int j = 0; j < 8; ++j) acc[i][j] = (f32x4){0.f, 0.f, 0.f, 0.f};

  const int swz = (l15 & 7);                       // row&7 == l15&7 for all fragment rows
  const int arow = waveM * 64 + l15;
  const int brow = waveN * 128 + l15;

  float4 ra0, ra1, ra2, ra3;
  auto issueA = [&](int k0) {
    int g0 = k0 + cA * 8;
    int g1 = k0 + (cA + 4) * 8;
    int g0c = g0 < D_IN ? g0 : 0;   // clamp: always issue (vmcnt determinism)
    int g1c = g1 < D_IN ? g1 : 0;
    ra0 = *(const float4*)(gArow + g0c);
    ra1 = *(const float4*)(gArow + g0c + 4);
    ra2 = *(const float4*)(gArow + g1c);
    ra3 = *(const float4*)(gArow + g1c + 4);
  };
  auto writeA = [&](int k0) {
    float4 a0 = ra0, a1 = ra1, b0 = ra2, b1 = ra3;
    if (k0 + cA * 8 >= D_IN)       { a0 = (float4){0.f,0.f,0.f,0.f}; a1 = a0; }
    if (k0 + (cA + 4) * 8 >= D_IN) { b0 = (float4){0.f,0.f,0.f,0.f}; b1 = b0; }
    f16x8 o0, o1;
    o0[0]=(f16)a0.x; o0[1]=(f16)a0.y; o0[2]=(f16)a0.z; o0[3]=(f16)a0.w;
    o0[4]=(f16)a1.x; o0[5]=(f16)a1.y; o0[6]=(f16)a1.z; o0[7]=(f16)a1.w;
    o1[0]=(f16)b0.x; o1[1]=(f16)b0.y; o1[2]=(f16)b0.z; o1[3]=(f16)b0.w;
    o1[4]=(f16)b1.x; o1[5]=(f16)b1.y; o1[6]=(f16)b1.z; o1[7]=(f16)b1.w;
    *(f16x8*)((f16*)lds_all + wA0) = o0;
    *(f16x8*)((f16*)lds_all + wA1) = o1;
  };
  auto issueB = [&](int k0, int bOff) {
    f16* Bs_ = (f16*)(lds_all + bOff);
    #pragma unroll
    for (int i = 0; i < 8; ++i) gld_lds16(gBp[i] + k0, Bs_ + lBoff[i]);
  };
  auto mma = [&](int bOff) {
    const f16* As_ = (const f16*)lds_all;
    const f16* Bs_ = (const f16*)(lds_all + bOff);
    #pragma unroll
    for (int ks = 0; ks < 2; ++ks) {               // ascending k within BK=64
      const int coff = ((ks * 4 + quad) ^ swz) * 8;
      f16x8 af[4], bf[8];
      #pragma unroll
      for (int i = 0; i < 4; ++i) af[i] = *(const f16x8*)(As_ + (arow + i * 16) * 64 + coff);
      #pragma unroll
      for (int j = 0; j < 8; ++j) bf[j] = *(const f16x8*)(Bs_ + (brow + j * 16) * 64 + coff);
      #pragma unroll
      for (int i = 0; i < 4; ++i)
        #pragma unroll
        for (int j = 0; j < 8; ++j)
          acc[i][j] = __builtin_amdgcn_mfma_f32_16x16x32_f16(af[i], bf[j], acc[i][j], 0, 0, 0);
    }
  };

  const int NT = KP / 64;                   // 13
  // prologue: A(0) to regs, B(0) to stage0
  issueA(0);  MEMFENCE;
  issueB(0, 16384); MEMFENCE;

  for (int k = 0; k < NT; ++k) {
    BARRIER();                              // (a) prior mma done reading A-buf & next B-stage
    writeA(k * 64);                         // implicit vmcnt: retire A(k) regs only
    MEMFENCE;
    if (k + 1 < NT) {
      issueA((k + 1) * 64); MEMFENCE;
      issueB((k + 1) * 64, 16384 + ((k + 1) & 1) * 65536); MEMFENCE;
      asm volatile("s_waitcnt vmcnt(12) lgkmcnt(0)" ::: "memory");  // B(k) landed
    } else {
      asm volatile("s_waitcnt vmcnt(0) lgkmcnt(0)" ::: "memory");
    }
    BARRIER();                              // (b) A(k) visible, B(k) ready
    __builtin_amdgcn_s_setprio(1);
    mma(16384 + (k & 1) * 65536);
    __builtin_amdgcn_s_setprio(0);
  }
  __syncthreads();                          // protect staging before ht overwrite

  // epilogue: relu+bias -> ht (f16) + per-column stats on fp32 values
  const int colbase = waveN * 128 + l15;
  float bcol[8];
  #pragma unroll
  for (int j = 0; j < 8; ++j) bcol[j] = bias[colbase + j * 16];
  float cs[8], cs2[8];
  #pragma unroll
  for (int j = 0; j < 8; ++j) { cs[j] = 0.f; cs2[j] = 0.f; }
  #pragma unroll
  for (int i = 0; i < 4; ++i)
    #pragma unroll
    for (int r2 = 0; r2 < 4; ++r2) {
      int rloc = waveM * 64 + i * 16 + quad * 4 + r2;
      #pragma unroll
      for (int j = 0; j < 8; ++j) {
        float v = acc[i][j][r2] + bcol[j];
        v = v > 0.f ? v : 0.f;
        ht[rloc * HT_LD + waveN * 128 + j * 16 + l15] = (f16)v;
        cs[j] += v; cs2[j] += v * v;
      }
    }
  #pragma unroll
  for (int j = 0; j < 8; ++j) {
    cs[j]  += __shfl_xor(cs[j], 16, 64);  cs[j]  += __shfl_xor(cs[j], 32, 64);
    cs2[j] += __shfl_xor(cs2[j], 16, 64); cs2[j] += __shfl_xor(cs2[j], 32, 64);
  }
  if (quad == 0) {
    #pragma unroll
    for (int j = 0; j < 8; ++j) {
      atomicAdd(&cls[waveN * 128 + j * 16 + l15], cs[j]);
      atomicAdd(&cls2[waveN * 128 + j * 16 + l15], cs2[j]);
    }
  }
  __syncthreads();
  atomicAdd(&statacc[256 + tid], cls[tid]);
  atomicAdd(&statacc[768 + tid], cls2[tid]);
  // coalesced h write-back: wave w -> rows w*16..w*16+15; one 1KB row per store
  #pragma unroll
  for (int rr = 0; rr < 16; ++rr) {
    int row = wid * 16 + rr;
    f16x8 vrow = *(const f16x8*)(ht + row * HT_LD + lane * 8);
    *(f16x8*)(C + (size_t)(bm * 128 + row) * HDIM + lane * 8) = vrow;
  }
}

// ---------------- BN coefficients + diff output + W3 f16 (padded 10->16 rows) ----------------
__global__ void k_bnprep(const float* __restrict__ acc, const float* __restrict__ gamma,
                         const float* __restrict__ beta, float* __restrict__ ab,
                         const float* __restrict__ W3, f16* __restrict__ W3h,
                         float* __restrict__ diff_out) {
  const int c = threadIdx.x;                        // 512 threads
  const float inv = 1.f / 65536.f;
  float mu = acc[256 + c] * inv;
  float msq = acc[768 + c] * inv;
  float var = msq - mu * mu;
  float a = gamma[c] / sqrtf(var + 1e-5f);
  ab[c] = a;
  ab[512 + c] = beta[c] - mu * a;
  #pragma unroll
  for (int o = 0; o < 16; ++o)
    W3h[o * HDIM + c] = (o < D_OUT) ? (f16)W3[o * HDIM + c] : (f16)0.f;
  if (c == 0) {
    float s1 = 0.f, s2 = 0.f;
    for (int i = 0; i < 128; ++i) { s1 += acc[i]; s2 += acc[128 + i]; }
    diff_out[0] = s1 * (1.f / 401408.f) + s2 * (1.f / 262144.f);
  }
}

// ---------------- fold BN into qW2 (in place) + bias2 ----------------
__global__ void k_bnfold(f16* __restrict__ qW2, const float* __restrict__ ab,
                         const float* __restrict__ b2, float* __restrict__ bias2) {
  __shared__ float red[256];
  const int n = blockIdx.x, t = threadIdx.x;        // 512 blocks x 256 threads
  float partial = 0.f;
  #pragma unroll
  for (int kk = 0; kk < 2; ++kk) {
    int k = t + kk * 256;
    float w = (float)qW2[n * HDIM + k];
    partial += ab[512 + k] * w;
    qW2[n * HDIM + k] = (f16)(ab[k] * w);
  }
  red[t] = partial; __syncthreads();
  for (int s = 128; s > 0; s >>= 1) { if (t < s) red[t] += red[t + s]; __syncthreads(); }
  if (t == 0) bias2[n] = b2[n] + red[0];
}

// ---------------- GEMM2 + fused final layer ----------------
// Same BK=64 / A-single-buf / B-double-buf structure (A reg-staged f16, no cvt).
// K=512 -> 8 iters. Full K in-block -> direct out stores.
// Ledger: A 2 loads, B 8 -> steady explicit vmcnt(10).
__global__ void __launch_bounds__(512, 2)
k_gemm2f(const f16* __restrict__ A, const f16* __restrict__ Bw,
         const float* __restrict__ bias2, const f16* __restrict__ W3h,
         const float* __restrict__ b3, float* __restrict__ out) {
  __shared__ __align__(16) char lds_all[147456];
  f16* ht = (f16*)lds_all;
  const int tid = threadIdx.x;
  const int bm = blockIdx.x;
  const int lane = tid & 63, wid = tid >> 6;
  const int waveM = wid & 1, waveN = wid >> 1;
  const int l15 = lane & 15, quad = lane >> 4;

  const int rA = tid >> 2, cA = tid & 3;
  const f16* gArow = A + (size_t)(bm * 128 + rA) * HDIM;
  const int wA0 = rA * 64 + ((cA ^ (rA & 7)) * 8);
  const int wA1 = rA * 64 + (((cA + 4) ^ (rA & 7)) * 8);
  const f16* gBp[8]; int lBoff[8];
  #pragma unroll
  for (int i = 0; i < 8; ++i) {
    int s = tid + i * 512;
    int rB = s >> 3, cB = s & 7;
    gBp[i] = Bw + (size_t)rB * HDIM + ((cB ^ (rB & 7)) * 8);
    lBoff[i] = s * 8;
  }

  f32x4 acc[4][8];
  #pragma unroll
  for (int i = 0; i < 4; ++i)
    #pragma unroll
    for (int j = 0; j < 8; ++j) acc[i][j] = (f32x4){0.f, 0.f, 0.f, 0.f};

  const int swz = (l15 & 7);
  const int arow = waveM * 64 + l15;
  const int brow = waveN * 128 + l15;

  f16x8 ra0, ra1;
  auto issueA = [&](int k0) {
    ra0 = *(const f16x8*)(gArow + k0 + cA * 8);
    ra1 = *(const f16x8*)(gArow + k0 + (cA + 4) * 8);
  };
  auto writeA = [&]() {
    *(f16x8*)((f16*)lds_all + wA0) = ra0;
    *(f16x8*)((f16*)lds_all + wA1) = ra1;
  };
  auto issueB = [&](int k0, int bOff) {
    f16* Bs_ = (f16*)(lds_all + bOff);
    #pragma unroll
    for (int i = 0; i < 8; ++i) gld_lds16(gBp[i] + k0, Bs_ + lBoff[i]);
  };
  auto mma = [&](int bOff) {
    const f16* As_ = (const f16*)lds_all;
    const f16* Bs_ = (const f16*)(lds_all + bOff);
    #pragma unroll
    for (int ks = 0; ks < 2; ++ks) {
      const int coff = ((ks * 4 + quad) ^ swz) * 8;
      f16x8 af[4], bf[8];
      #pragma unroll
      for (int i = 0; i < 4; ++i) af[i] = *(const f16x8*)(As_ + (arow + i * 16) * 64 + coff);
      #pragma unroll
      for (int j = 0; j < 8; ++j) bf[j] = *(const f16x8*)(Bs_ + (brow + j * 16) * 64 + coff);
      #pragma unroll
      for (int i = 0; i < 4; ++i)
        #pragma unroll
        for (int j = 0; j < 8; ++j)
          acc[i][j] = __builtin_amdgcn_mfma_f32_16x16x32_f16(af[i], bf[j], acc[i][j], 0, 0, 0);
    }
  };

  const int NT = HDIM / 64;                 // 8
  issueA(0);  MEMFENCE;
  issueB(0, 16384); MEMFENCE;

  for (int k = 0; k < NT; ++k) {
    BARRIER();
    writeA();
    MEMFENCE;
    if (k + 1 < NT) {
      issueA((k + 1) * 64); MEMFENCE;
      issueB((k + 1) * 64, 16384 + ((k + 1) & 1) * 65536); MEMFENCE;
      asm volatile("s_waitcnt vmcnt(10) lgkmcnt(0)" ::: "memory");
    } else {
      asm volatile("s_waitcnt vmcnt(0) lgkmcnt(0)" ::: "memory");
    }
    BARRIER();
    __builtin_amdgcn_s_setprio(1);
    mma(16384 + (k & 1) * 65536);
    __builtin_amdgcn_s_setprio(0);
  }
  __syncthreads();

  // epilogue: relu+bias2 -> ht (f16)
  const int colbase = waveN * 128 + l15;
  float bcol[8];
  #pragma unroll
  for (int j = 0; j < 8; ++j) bcol[j] = bias2[colbase + j * 16];
  #pragma unroll
  for (int i = 0; i < 4; ++i)
    #pragma unroll
    for (int r2 = 0; r2 < 4; ++r2) {
      int rloc = waveM * 64 + i * 16 + quad * 4 + r2;
      #pragma unroll
      for (int j = 0; j < 8; ++j) {
        float v = acc[i][j][r2] + bcol[j];
        v = v > 0.f ? v : 0.f;
        ht[rloc * HT_LD + waveN * 128 + j * 16 + l15] = (f16)v;
      }
    }
  __syncthreads();
  // final layer: wave w -> rows w*16..w*16+15; full K=512 in-block; direct store.
  f32x4 oacc = (f32x4){0.f, 0.f, 0.f, 0.f};
  #pragma unroll
  for (int ks = 0; ks < 16; ++ks) {
    f16x8 bfr = *(const f16x8*)(W3h + l15 * HDIM + ks * 32 + quad * 8);
    f16x8 afr = *(const f16x8*)(ht + (wid * 16 + l15) * HT_LD + ks * 32 + quad * 8);
    oacc = __builtin_amdgcn_mfma_f32_16x16x32_f16(afr, bfr, oacc, 0, 0, 0);
  }
  if (l15 < D_OUT) {
    float badd = b3[l15];
    #pragma unroll
    for (int r2 = 0; r2 < 4; ++r2) {
      int row = bm * 128 + wid * 16 + quad * 4 + r2;
      out[(size_t)row * D_OUT + l15] = oacc[r2] + badd;
    }
  }
}

extern "C" void kernel_launch(void* const* d_in, const int* in_sizes, int n_in,
                              void* d_out, int out_size, void* d_ws, size_t ws_size,
                              hipStream_t stream) {
  const float* x     = (const float*)d_in[0];
  const float* W1    = (const float*)d_in[1];
  const float* b1    = (const float*)d_in[2];
  const float* gamma = (const float*)d_in[3];
  const float* beta  = (const float*)d_in[4];
  const float* E1    = (const float*)d_in[5];
  const float* W2    = (const float*)d_in[6];
  const float* b2    = (const float*)d_in[7];
  const float* E2    = (const float*)d_in[8];
  const float* W3    = (const float*)d_in[9];
  const float* b3    = (const float*)d_in[10];
  float* out = (float*)d_out;

  char* ws = (char*)d_ws;
  float* accum = (float*)ws;                       // [0,128) diff1, [128,256) diff2, [256,768) colsum, [768,1280) colsumsq
  f16* qW1h = (f16*)(ws + 8192);                   // 512*832*2 = 851968
  f16* qW2h = (f16*)(ws + 860160);                 // 512*512*2 = 524288
  f16* W3h  = (f16*)(ws + 1384448);                // 16*512*2  = 16384
  float* ab = (float*)(ws + 1400832);              // 1024*4
  float* bias2 = (float*)(ws + 1404928);           // 512*4
  f16* h    = (f16*)(ws + 1409024);                // 65536*512*2 = 67108864

  (void)hipMemsetAsync(ws, 0, 860160, stream);     // accum + qW1h (zero K-padding)
  k_vq1<<<3584, 256, 0, stream>>>(W1, E1, qW1h, accum);
  k_vq2<<<4096, 256, 0, stream>>>(W2, E2, qW2h, accum + 128);
  k_gemm1<<<512, 512, 0, stream>>>(x, qW1h, b1, h, accum);
  k_bnprep<<<1, 512, 0, stream>>>(accum, gamma, beta, ab, W3, W3h, out + (size_t)BATCH * D_OUT);
  k_bnfold<<<512, 256, 0, stream>>>(qW2h, ab, b2, bias2);
  k_gemm2f<<<512, 512, 0, stream>>>(h, qW2h, bias2, W3h, b3, out);
}